// Round 2
// baseline (18041.837 us; speedup 1.0000x reference)
//
#include <hip/hip_runtime.h>
#include <hip/hip_cooperative_groups.h>

namespace cg = cooperative_groups;

#define B_ 256
#define T_ 512
#define I_ 512
#define H_ 1024
#define O_ 128
#define BT_ (B_*T_)

typedef short s16x8 __attribute__((ext_vector_type(8)));
typedef float f32x4 __attribute__((ext_vector_type(4)));

#define MFMA16(a,b,c) __builtin_amdgcn_mfma_f32_16x16x32_bf16(a, b, c, 0, 0, 0)

__device__ __forceinline__ short f2bf(float x){
  unsigned u = __float_as_uint(x);
  u = u + 0x7FFFu + ((u >> 16) & 1u);
  return (short)(u >> 16);
}
__device__ __forceinline__ float bf2f(short h){
  return __uint_as_float(((unsigned)(unsigned short)h) << 16);
}

// Convert 16 consecutive fp32 -> 16 bf16 and store to LDS (two 16B stores).
__device__ __forceinline__ void stage16(const float* __restrict__ src, short* dst){
  float4 v0 = *(const float4*)(src + 0);
  float4 v1 = *(const float4*)(src + 4);
  float4 v2 = *(const float4*)(src + 8);
  float4 v3 = *(const float4*)(src + 12);
  s16x8 t0 = { f2bf(v0.x), f2bf(v0.y), f2bf(v0.z), f2bf(v0.w),
               f2bf(v1.x), f2bf(v1.y), f2bf(v1.z), f2bf(v1.w) };
  s16x8 t1 = { f2bf(v2.x), f2bf(v2.y), f2bf(v2.z), f2bf(v2.w),
               f2bf(v3.x), f2bf(v3.y), f2bf(v3.z), f2bf(v3.w) };
  *(s16x8*)(dst)     = t0;
  *(s16x8*)(dst + 8) = t1;
}

// ---------------- phase 1: xw = x @ W_in^T + b_in  ->  hid ----------------
__global__ __launch_bounds__(256) void gemm_xw(const float* __restrict__ A,
                                               const float* __restrict__ Wn,
                                               const float* __restrict__ bias,
                                               float* __restrict__ out){
  __shared__ __align__(16) short As[128][40];
  __shared__ __align__(16) short Bs[128][40];
  int bm = blockIdx.x, bn = blockIdx.y;
  int tid = threadIdx.x;
  int lane = tid & 63, wave = tid >> 6;
  int wm = wave >> 1, wn = wave & 1;
  int row0 = bm * 128, col0 = bn * 128;

  f32x4 acc[4][4] = {};
  int sr = tid >> 1, ss = (tid & 1) * 16;

  for (int k0 = 0; k0 < I_; k0 += 32){
    stage16(A  + (size_t)(row0 + sr) * I_ + k0 + ss, &As[sr][ss]);
    stage16(Wn + (size_t)(col0 + sr) * I_ + k0 + ss, &Bs[sr][ss]);
    __syncthreads();

    int rsel = lane & 15, ko = (lane >> 4) * 8;
    s16x8 af[4], bf[4];
    #pragma unroll
    for (int f = 0; f < 4; ++f){
      af[f] = *(const s16x8*)&As[wm*64 + f*16 + rsel][ko];
      bf[f] = *(const s16x8*)&Bs[wn*64 + f*16 + rsel][ko];
    }
    #pragma unroll
    for (int fm = 0; fm < 4; ++fm)
      #pragma unroll
      for (int fn = 0; fn < 4; ++fn)
        acc[fm][fn] = MFMA16(af[fm], bf[fn], acc[fm][fn]);
    __syncthreads();
  }

  int rbase = (lane >> 4) * 4, cbase = lane & 15;
  #pragma unroll
  for (int fm = 0; fm < 4; ++fm)
    #pragma unroll
    for (int fn = 0; fn < 4; ++fn){
      int gcol = col0 + wn*64 + fn*16 + cbase;
      float b = bias[gcol];
      #pragma unroll
      for (int r = 0; r < 4; ++r){
        int grow = row0 + wm*64 + fm*16 + rbase + r;
        out[(size_t)grow * H_ + gcol] = acc[fm][fn][r] + b;
      }
    }
}

// ---------------- phase 2: persistent recurrence kernel ----------------
// Grid: 256 wgs = 8 batch-groups x 32 col-groups. 512 threads = 8 waves:
// kw = wave>>2 (K half), wm = (wave>>1)&1, wn = wave&1. Wave tile 16x16.
// W_h slice (32 cols x 1024 K, hi+lo bf16, XOR-swizzled) resident in LDS.
// h hi/lo planes ping-pong in global scratch; one grid sync per step.
__global__ __launch_bounds__(512, 2) void rnn_persistent(float* __restrict__ hid,
                                                         const float* __restrict__ Wh,
                                                         const float* __restrict__ bh,
                                                         short* __restrict__ planes){
  __shared__ __align__(16) short Ws[2][32][1024];   // 128 KB: [plane][col][k^swz]
  __shared__ __align__(16) float red[4][64][4];     // 4 KB cross-wave K-reduce

  const int PLANE = B_ * H_;
  int bid = blockIdx.x;
  int bg = bid >> 5;           // batch group 0..7
  int cg = bid & 31;           // col group 0..31
  int tid = threadIdx.x;
  int l = tid & 63, wave = tid >> 6;
  int kw = wave >> 2, wm = (wave >> 1) & 1, wn = wave & 1;
  int pair = wm * 2 + wn;

  // ---- load + split W_h slice into LDS (once) ----
  #pragma unroll
  for (int it = 0; it < 4; ++it){
    int idx = it * 8192 + tid * 16;          // 32 rows x 1024 k
    int row = idx >> 10;
    int kb  = idx & 1023;
    const float* src = Wh + (size_t)(cg*32 + row) * H_ + kb;
    #pragma unroll
    for (int g = 0; g < 2; ++g){
      float4 v0 = *(const float4*)(src + g*8);
      float4 v1 = *(const float4*)(src + g*8 + 4);
      float vs[8] = {v0.x, v0.y, v0.z, v0.w, v1.x, v1.y, v1.z, v1.w};
      s16x8 hi8, lo8;
      #pragma unroll
      for (int e = 0; e < 8; ++e){
        short h = f2bf(vs[e]);
        hi8[e] = h;
        lo8[e] = f2bf(vs[e] - bf2f(h));
      }
      int ks = (kb + g*8) ^ ((row & 7) << 3);
      *(s16x8*)&Ws[0][row][ks] = hi8;
      *(s16x8*)&Ws[1][row][ks] = lo8;
    }
  }
  __syncthreads();

  int gcol  = cg*32 + wn*16 + (l & 15);      // output column (global)
  int ci    = wn*16 + (l & 15);              // LDS-local col
  int ab    = bg*32 + wm*16 + (l & 15);      // A-fragment batch row
  int brow0 = bg*32 + wm*16 + (l >> 4) * 4;  // epilogue batch base
  float bias_c = bh[gcol];
  int kofs = kw*512 + (l >> 4) * 8;

  cg::grid_group grid = cg::this_grid();

  for (int t = 0; t < T_; ++t){
    int s_in = t & 1, s_out = (t + 1) & 1;
    const short* inHi = planes + (size_t)s_in * 2 * PLANE;
    const short* inLo = inHi + PLANE;
    short* outHi = planes + (size_t)s_out * 2 * PLANE;
    short* outLo = outHi + PLANE;

    if (t > 0) grid.sync();

    f32x4 accT = {};

    if (t > 0){
      // A fragments: h_{t-1} hi/lo, direct global->reg (L2/L3 resident)
      const short* hi_b = inHi + (size_t)ab * H_ + kofs;
      const short* lo_b = inLo + (size_t)ab * H_ + kofs;
      s16x8 aHi[16], aLo[16];
      #pragma unroll
      for (int kc = 0; kc < 16; ++kc) aHi[kc] = *(const s16x8*)(hi_b + kc*32);
      #pragma unroll
      for (int kc = 0; kc < 16; ++kc) aLo[kc] = *(const s16x8*)(lo_b + kc*32);

      // xw[t] for epilogue: issue early, HBM latency hides under K loop
      float xwv[4] = {0.f, 0.f, 0.f, 0.f};
      if (kw == 0){
        #pragma unroll
        for (int j = 0; j < 4; ++j)
          xwv[j] = hid[((size_t)(brow0 + j) * T_ + t) * H_ + gcol];
      }

      f32x4 ac0 = {}, ac1 = {}, ac2 = {};
      #pragma unroll
      for (int kc = 0; kc < 16; ++kc){
        int k = kofs + kc*32;
        const short* bp = &Ws[0][ci][k ^ ((ci & 7) << 3)];
        s16x8 bhv = *(const s16x8*)bp;
        s16x8 blv = *(const s16x8*)(bp + 32*1024);
        ac0 = MFMA16(aHi[kc], bhv, ac0);
        ac1 = MFMA16(aHi[kc], blv, ac1);
        ac2 = MFMA16(aLo[kc], bhv, ac2);
      }
      accT = ac0 + ac1;
      accT = accT + ac2;

      if (kw == 1) *(f32x4*)&red[pair][l][0] = accT;
      __syncthreads();
      if (kw == 0) accT = accT + *(const f32x4*)&red[pair][l][0];

      if (kw == 0){
        #pragma unroll
        for (int j = 0; j < 4; ++j){
          float v = accT[j] + xwv[j] + bias_c;
          v = v > 0.0f ? v : 0.0f;
          hid[((size_t)(brow0 + j) * T_ + t) * H_ + gcol] = v;
          short hi_ = f2bf(v);
          outHi[(size_t)(brow0 + j) * H_ + gcol] = hi_;
          outLo[(size_t)(brow0 + j) * H_ + gcol] = f2bf(v - bf2f(hi_));
        }
      }
    } else {
      // t == 0: h_prev = 0
      if (kw == 0){
        #pragma unroll
        for (int j = 0; j < 4; ++j){
          size_t idx = ((size_t)(brow0 + j) * T_ + t) * H_ + gcol;
          float v = hid[idx] + bias_c;
          v = v > 0.0f ? v : 0.0f;
          hid[idx] = v;
          short hi_ = f2bf(v);
          outHi[(size_t)(brow0 + j) * H_ + gcol] = hi_;
          outLo[(size_t)(brow0 + j) * H_ + gcol] = f2bf(v - bf2f(hi_));
        }
      }
    }
  }
}

// ---------------- phase 3: out = hidden @ W_o^T + b_o ----------------
__global__ __launch_bounds__(256) void gemm_out(const float* __restrict__ A,
                                                const float* __restrict__ Wo,
                                                const float* __restrict__ bias,
                                                float* __restrict__ out){
  __shared__ __align__(16) short As[128][40];
  __shared__ __align__(16) short Bs[128][40];
  int bm = blockIdx.x;
  int tid = threadIdx.x;
  int lane = tid & 63, wave = tid >> 6;
  int wm = wave >> 1, wn = wave & 1;
  int row0 = bm * 128;

  f32x4 acc[4][4] = {};
  int sr = tid >> 1, ss = (tid & 1) * 16;

  for (int k0 = 0; k0 < H_; k0 += 32){
    stage16(A  + (size_t)(row0 + sr) * H_ + k0 + ss, &As[sr][ss]);
    stage16(Wo + (size_t)sr * H_ + k0 + ss, &Bs[sr][ss]);
    __syncthreads();

    int rsel = lane & 15, ko = (lane >> 4) * 8;
    s16x8 af[4], bf[4];
    #pragma unroll
    for (int f = 0; f < 4; ++f){
      af[f] = *(const s16x8*)&As[wm*64 + f*16 + rsel][ko];
      bf[f] = *(const s16x8*)&Bs[wn*64 + f*16 + rsel][ko];
    }
    #pragma unroll
    for (int fm = 0; fm < 4; ++fm)
      #pragma unroll
      for (int fn = 0; fn < 4; ++fn)
        acc[fm][fn] = MFMA16(af[fm], bf[fn], acc[fm][fn]);
    __syncthreads();
  }

  int rbase = (lane >> 4) * 4, cbase = lane & 15;
  #pragma unroll
  for (int fm = 0; fm < 4; ++fm)
    #pragma unroll
    for (int fn = 0; fn < 4; ++fn){
      int gcol = wn*64 + fn*16 + cbase;
      float b = bias[gcol];
      #pragma unroll
      for (int r = 0; r < 4; ++r){
        int grow = row0 + wm*64 + fm*16 + rbase + r;
        out[(size_t)grow * O_ + gcol] = acc[fm][fn][r] + b;
      }
    }
}

extern "C" void kernel_launch(void* const* d_in, const int* in_sizes, int n_in,
                              void* d_out, int out_size, void* d_ws, size_t ws_size,
                              hipStream_t stream) {
  const float* x    = (const float*)d_in[0];
  const float* W_in = (const float*)d_in[1];
  const float* b_in = (const float*)d_in[2];
  const float* W_h  = (const float*)d_in[3];
  const float* b_h  = (const float*)d_in[4];
  const float* W_o  = (const float*)d_in[5];
  const float* b_o  = (const float*)d_in[6];

  float* out = (float*)d_out;
  float* hid = out + (size_t)BT_ * O_;   // hidden_all region (B,T,H)

  // h hi/lo ping-pong planes stashed in the (B,T,O) output region (dead
  // until phase 3): 2 slots x (hi+lo) x 256*1024 shorts = 2 MB.
  short* planes = (short*)d_out;

  gemm_xw<<<dim3(BT_/128, H_/128), 256, 0, stream>>>(x, W_in, b_in, hid);

  {
    float* hid_p = hid;
    const float* Wh_p = W_h;
    const float* bh_p = b_h;
    short* planes_p = planes;
    void* args[] = { &hid_p, &Wh_p, &bh_p, &planes_p };
    hipLaunchCooperativeKernel((const void*)rnn_persistent,
                               dim3(256), dim3(512), args, 0, stream);
  }

  gemm_out<<<dim3(BT_/128), 256, 0, stream>>>(hid, W_o, b_o, out);
}

// Round 3
// 13339.149 us; speedup vs baseline: 1.3525x; 1.3525x over previous
//
#include <hip/hip_runtime.h>

#define B_ 256
#define T_ 512
#define I_ 512
#define H_ 1024
#define O_ 128
#define BT_ (B_*T_)

typedef short s16x8 __attribute__((ext_vector_type(8)));
typedef float f32x4 __attribute__((ext_vector_type(4)));

#define MFMA16(a,b,c) __builtin_amdgcn_mfma_f32_16x16x32_bf16(a, b, c, 0, 0, 0)

__device__ __forceinline__ short f2bf(float x){
  unsigned u = __float_as_uint(x);
  u = u + 0x7FFFu + ((u >> 16) & 1u);
  return (short)(u >> 16);
}
__device__ __forceinline__ float bf2f(short h){
  return __uint_as_float(((unsigned)(unsigned short)h) << 16);
}

__device__ __forceinline__ void stage16(const float* __restrict__ src, short* dst){
  float4 v0 = *(const float4*)(src + 0);
  float4 v1 = *(const float4*)(src + 4);
  float4 v2 = *(const float4*)(src + 8);
  float4 v3 = *(const float4*)(src + 12);
  s16x8 t0 = { f2bf(v0.x), f2bf(v0.y), f2bf(v0.z), f2bf(v0.w),
               f2bf(v1.x), f2bf(v1.y), f2bf(v1.z), f2bf(v1.w) };
  s16x8 t1 = { f2bf(v2.x), f2bf(v2.y), f2bf(v2.z), f2bf(v2.w),
               f2bf(v3.x), f2bf(v3.y), f2bf(v3.z), f2bf(v3.w) };
  *(s16x8*)(dst)     = t0;
  *(s16x8*)(dst + 8) = t1;
}

// ---------------- init: zero the barrier counters ----------------
__global__ void init_cnt(int* __restrict__ cnt){
  cnt[threadIdx.x] = 0;
}

// ---------------- phase 1: xw = x @ W_in^T + b_in  ->  hid ----------------
__global__ __launch_bounds__(256) void gemm_xw(const float* __restrict__ A,
                                               const float* __restrict__ Wn,
                                               const float* __restrict__ bias,
                                               float* __restrict__ out){
  __shared__ __align__(16) short As[128][40];
  __shared__ __align__(16) short Bs[128][40];
  int bm = blockIdx.x, bn = blockIdx.y;
  int tid = threadIdx.x;
  int lane = tid & 63, wave = tid >> 6;
  int wm = wave >> 1, wn = wave & 1;
  int row0 = bm * 128, col0 = bn * 128;

  f32x4 acc[4][4] = {};
  int sr = tid >> 1, ss = (tid & 1) * 16;

  for (int k0 = 0; k0 < I_; k0 += 32){
    stage16(A  + (size_t)(row0 + sr) * I_ + k0 + ss, &As[sr][ss]);
    stage16(Wn + (size_t)(col0 + sr) * I_ + k0 + ss, &Bs[sr][ss]);
    __syncthreads();

    int rsel = lane & 15, ko = (lane >> 4) * 8;
    s16x8 af[4], bf[4];
    #pragma unroll
    for (int f = 0; f < 4; ++f){
      af[f] = *(const s16x8*)&As[wm*64 + f*16 + rsel][ko];
      bf[f] = *(const s16x8*)&Bs[wn*64 + f*16 + rsel][ko];
    }
    #pragma unroll
    for (int fm = 0; fm < 4; ++fm)
      #pragma unroll
      for (int fn = 0; fn < 4; ++fn)
        acc[fm][fn] = MFMA16(af[fm], bf[fn], acc[fm][fn]);
    __syncthreads();
  }

  int rbase = (lane >> 4) * 4, cbase = lane & 15;
  #pragma unroll
  for (int fm = 0; fm < 4; ++fm)
    #pragma unroll
    for (int fn = 0; fn < 4; ++fn){
      int gcol = col0 + wn*64 + fn*16 + cbase;
      float b = bias[gcol];
      #pragma unroll
      for (int r = 0; r < 4; ++r){
        int grow = row0 + wm*64 + fm*16 + rbase + r;
        out[(size_t)grow * H_ + gcol] = acc[fm][fn][r] + b;
      }
    }
}

// ---------------- phase 2: persistent recurrence, per-batch-group barrier ----
// Grid 256 wgs = 8 batch-groups (bg) x 32 col-groups (cgp). 512 thr = 8 waves:
// wm = wave>>2 (16-row half of the 32-batch tile), kw = wave&3 (K quarter).
// Each wave computes a 16x32 tile over K=256 (both wn halves), 3-product
// split bf16. W_h slice lives in LDS in FRAGMENT-MAJOR layout: 1KB blocks
// indexed (kw,kc,wn,plane), lane-linear 16B -> conflict-free ds_read_b128
// with a single base reg + immediate offsets.
// Sync: per-bg monotonic counter in global scratch; arrive after epilogue,
// tid0 spins, xw(t+1) prefetched under the spin.
__global__ __launch_bounds__(512, 2) void rnn_persistent(float* __restrict__ hid,
                                                         const float* __restrict__ Wh,
                                                         const float* __restrict__ bh,
                                                         short* __restrict__ planes,
                                                         int* __restrict__ cnt){
  __shared__ __align__(16) short Wf[65536];              // 128 KB fragment-major
  __shared__ __align__(16) float red[2][4][2][64][4];    // 16 KB K-reduce

  const int PLANE = B_ * H_;                 // 262144 shorts
  int bid = blockIdx.x;
  int bg  = bid >> 5;                        // 0..7
  int cgp = bid & 31;                        // 0..31
  int tid = threadIdx.x;
  int l = tid & 63, wave = tid >> 6;
  int wm = wave >> 2, kw = wave & 3;

  // ---- preload W_h slice, split hi/lo, store fragment-major (once) ----
  #pragma unroll
  for (int it = 0; it < 4; ++it){
    int idx = it * 8192 + tid * 16;          // 32 cols x 1024 k
    int col = idx >> 10;                     // Wh row = output col (0..31)
    int kb  = idx & 1023;                    // multiple of 16
    const float* src = Wh + (size_t)(cgp*32 + col) * H_ + kb;
    int kwW = kb >> 8, kcW = (kb >> 5) & 7, gW = (kb >> 3) & 3;
    int wnW = col >> 4;
    int blk = (kwW*8 + kcW)*4 + wnW*2;       // +p
    #pragma unroll
    for (int h = 0; h < 2; ++h){
      float4 v0 = *(const float4*)(src + h*8);
      float4 v1 = *(const float4*)(src + h*8 + 4);
      float vs[8] = {v0.x, v0.y, v0.z, v0.w, v1.x, v1.y, v1.z, v1.w};
      s16x8 hi8, lo8;
      #pragma unroll
      for (int e = 0; e < 8; ++e){
        short hh = f2bf(vs[e]);
        hi8[e] = hh;
        lo8[e] = f2bf(vs[e] - bf2f(hh));
      }
      int lane16 = ((gW + h) << 4) | (col & 15);
      *(s16x8*)&Wf[(size_t)(blk + 0)*512 + lane16*8] = hi8;
      *(s16x8*)&Wf[(size_t)(blk + 1)*512 + lane16*8] = lo8;
    }
  }
  __syncthreads();

  // ---- per-thread constants ----
  int brow = bg*32 + wm*16 + ((l >> 4) << 2) + kw;   // epilogue batch row
  int gc0  = cgp*32 + (l & 15);                      // wn=0 column
  float bias0 = bh[gc0], bias1 = bh[gc0 + 16];
  float* hidRow = hid + (size_t)brow * T_ * H_;

  int arow = bg*32 + wm*16 + (l & 15);               // A-frag batch row
  int acol = kw*256 + ((l >> 4) << 3);               // A-frag k offset
  const size_t aoff = (size_t)arow * H_ + acol;
  const short* wb = Wf + kw*16384 + l*8;             // W frag base (this wave)

  int* c = cnt + bg * 32;                            // own group's counter

  // prefetch xw for t = 0
  float xw0 = hidRow[gc0], xw1 = hidRow[gc0 + 16];

  for (int t = 0; t < T_; ++t){
    f32x4 totA = {}, totB = {};

    if (t > 0){
      // wait for all 32 wgs of this batch group to finish step t-1
      if (tid == 0){
        while (__hip_atomic_load(c, __ATOMIC_RELAXED, __HIP_MEMORY_SCOPE_AGENT) < 32*t)
          __builtin_amdgcn_s_sleep(1);
        __threadfence();                             // acquire
      }
      __syncthreads();

      // A fragments: h_{t-1} hi/lo from plane slot t&1 (L2/L3 resident)
      const short* aH = planes + (size_t)(t & 1) * 2 * PLANE + aoff;
      const short* aL = aH + PLANE;
      s16x8 ah[8], al[8];
      #pragma unroll
      for (int kc = 0; kc < 8; ++kc) ah[kc] = *(const s16x8*)(aH + kc*32);
      #pragma unroll
      for (int kc = 0; kc < 8; ++kc) al[kc] = *(const s16x8*)(aL + kc*32);

      f32x4 p0 = {}, p1 = {}, p2 = {}, q0 = {}, q1 = {}, q2 = {};
      #pragma unroll
      for (int kc = 0; kc < 8; ++kc){
        s16x8 w0h = *(const s16x8*)(wb + (kc*4 + 0)*512);
        s16x8 w0l = *(const s16x8*)(wb + (kc*4 + 1)*512);
        s16x8 w1h = *(const s16x8*)(wb + (kc*4 + 2)*512);
        s16x8 w1l = *(const s16x8*)(wb + (kc*4 + 3)*512);
        p0 = MFMA16(ah[kc], w0h, p0);
        q0 = MFMA16(ah[kc], w1h, q0);
        p1 = MFMA16(ah[kc], w0l, p1);
        q1 = MFMA16(ah[kc], w1l, q1);
        p2 = MFMA16(al[kc], w0h, p2);
        q2 = MFMA16(al[kc], w1h, q2);
      }
      f32x4 accA = (p0 + p1) + p2;
      f32x4 accB = (q0 + q1) + q2;

      // cross-wave K reduce
      *(f32x4*)&red[wm][kw][0][l][0] = accA;
      *(f32x4*)&red[wm][kw][1][l][0] = accB;
      __syncthreads();
      #pragma unroll
      for (int kq = 0; kq < 4; ++kq){
        totA = totA + *(const f32x4*)&red[wm][kq][0][l][0];
        totB = totB + *(const f32x4*)&red[wm][kq][1][l][0];
      }
    }

    // ---- epilogue: row j = kw of this lane's 4-row group ----
    float v0 = totA[kw] + xw0 + bias0;
    float v1 = totB[kw] + xw1 + bias1;
    v0 = v0 > 0.0f ? v0 : 0.0f;
    v1 = v1 > 0.0f ? v1 : 0.0f;

    hidRow[(size_t)t * H_ + gc0]      = v0;
    hidRow[(size_t)t * H_ + gc0 + 16] = v1;

    short* pb = planes + (size_t)((t + 1) & 1) * 2 * PLANE + (size_t)brow * H_;
    short h0 = f2bf(v0), h1 = f2bf(v1);
    pb[gc0]              = h0;
    pb[gc0 + 16]         = h1;
    pb[PLANE + gc0]      = f2bf(v0 - bf2f(h0));
    pb[PLANE + gc0 + 16] = f2bf(v1 - bf2f(h1));

    // arrive (after all waves' stores are drained by the barrier)
    __syncthreads();
    if (tid == 0){
      __threadfence();                               // release
      __hip_atomic_fetch_add(c, 1, __ATOMIC_RELAXED, __HIP_MEMORY_SCOPE_AGENT);
    }

    // prefetch xw for t+1 — HBM latency hides under the spin
    int tn = (t + 1 < T_) ? t + 1 : t;
    xw0 = hidRow[(size_t)tn * H_ + gc0];
    xw1 = hidRow[(size_t)tn * H_ + gc0 + 16];
  }
}

// ---------------- phase 3: out = hidden @ W_o^T + b_o ----------------
__global__ __launch_bounds__(256) void gemm_out(const float* __restrict__ A,
                                                const float* __restrict__ Wo,
                                                const float* __restrict__ bias,
                                                float* __restrict__ out){
  __shared__ __align__(16) short As[128][40];
  __shared__ __align__(16) short Bs[128][40];
  int bm = blockIdx.x;
  int tid = threadIdx.x;
  int lane = tid & 63, wave = tid >> 6;
  int wm = wave >> 1, wn = wave & 1;
  int row0 = bm * 128;

  f32x4 acc[4][4] = {};
  int sr = tid >> 1, ss = (tid & 1) * 16;

  for (int k0 = 0; k0 < H_; k0 += 32){
    stage16(A  + (size_t)(row0 + sr) * H_ + k0 + ss, &As[sr][ss]);
    stage16(Wo + (size_t)sr * H_ + k0 + ss, &Bs[sr][ss]);
    __syncthreads();

    int rsel = lane & 15, ko = (lane >> 4) * 8;
    s16x8 af[4], bf[4];
    #pragma unroll
    for (int f = 0; f < 4; ++f){
      af[f] = *(const s16x8*)&As[wm*64 + f*16 + rsel][ko];
      bf[f] = *(const s16x8*)&Bs[wn*64 + f*16 + rsel][ko];
    }
    #pragma unroll
    for (int fm = 0; fm < 4; ++fm)
      #pragma unroll
      for (int fn = 0; fn < 4; ++fn)
        acc[fm][fn] = MFMA16(af[fm], bf[fn], acc[fm][fn]);
    __syncthreads();
  }

  int rbase = (lane >> 4) * 4, cbase = lane & 15;
  #pragma unroll
  for (int fm = 0; fm < 4; ++fm)
    #pragma unroll
    for (int fn = 0; fn < 4; ++fn){
      int gcol = wn*64 + fn*16 + cbase;
      float b = bias[gcol];
      #pragma unroll
      for (int r = 0; r < 4; ++r){
        int grow = row0 + wm*64 + fm*16 + rbase + r;
        out[(size_t)grow * O_ + gcol] = acc[fm][fn][r] + b;
      }
    }
}

extern "C" void kernel_launch(void* const* d_in, const int* in_sizes, int n_in,
                              void* d_out, int out_size, void* d_ws, size_t ws_size,
                              hipStream_t stream) {
  const float* x    = (const float*)d_in[0];
  const float* W_in = (const float*)d_in[1];
  const float* b_in = (const float*)d_in[2];
  const float* W_h  = (const float*)d_in[3];
  const float* b_h  = (const float*)d_in[4];
  const float* W_o  = (const float*)d_in[5];
  const float* b_o  = (const float*)d_in[6];

  float* out = (float*)d_out;
  float* hid = out + (size_t)BT_ * O_;       // hidden_all region (B,T,H)

  // Scratch inside the (B,T,O) output region (67 MB, dead until phase 3):
  //   planes: 2 slots x (hi+lo) x B_*H_ shorts = 2 MB at offset 0
  //   cnt:    8 barrier counters (32-int stride) at byte offset 4 MB
  short* planes = (short*)d_out;
  int*   cnt    = (int*)(out + (1 << 20));

  init_cnt<<<1, 256, 0, stream>>>(cnt);

  gemm_xw<<<dim3(BT_/128, H_/128), 256, 0, stream>>>(x, W_in, b_in, hid);

  {
    float* hid_p = hid;
    const float* Wh_p = W_h;
    const float* bh_p = b_h;
    short* planes_p = planes;
    int* cnt_p = cnt;
    void* args[] = { &hid_p, &Wh_p, &bh_p, &planes_p, &cnt_p };
    hipLaunchCooperativeKernel((const void*)rnn_persistent,
                               dim3(256), dim3(512), args, 0, stream);
  }

  gemm_out<<<dim3(BT_/128), 256, 0, stream>>>(hid, W_o, b_o, out);
}

// Round 4
// 5322.380 us; speedup vs baseline: 3.3898x; 2.5062x over previous
//
#include <hip/hip_runtime.h>

#define B_ 256
#define T_ 512
#define I_ 512
#define H_ 1024
#define O_ 128
#define BT_ (B_*T_)

typedef short s16x8 __attribute__((ext_vector_type(8)));
typedef float f32x4 __attribute__((ext_vector_type(4)));

#define MFMA16(a,b,c) __builtin_amdgcn_mfma_f32_16x16x32_bf16(a, b, c, 0, 0, 0)

__device__ __forceinline__ short f2bf(float x){
  unsigned u = __float_as_uint(x);
  u = u + 0x7FFFu + ((u >> 16) & 1u);
  return (short)(u >> 16);
}
__device__ __forceinline__ float bf2f(short h){
  return __uint_as_float(((unsigned)(unsigned short)h) << 16);
}

// Coherent (sc0 sc1) 16B load as 2x8B relaxed agent atomics: bypasses stale
// L1/L2 so cross-wg data is read from the coherence point (L3).
__device__ __forceinline__ s16x8 cload16(const short* p){
  union { unsigned long long u[2]; s16x8 v; } r;
  r.u[0] = __hip_atomic_load((unsigned long long*)p,       __ATOMIC_RELAXED, __HIP_MEMORY_SCOPE_AGENT);
  r.u[1] = __hip_atomic_load((unsigned long long*)(p + 4), __ATOMIC_RELAXED, __HIP_MEMORY_SCOPE_AGENT);
  return r.v;
}

__device__ __forceinline__ void stage16(const float* __restrict__ src, short* dst){
  float4 v0 = *(const float4*)(src + 0);
  float4 v1 = *(const float4*)(src + 4);
  float4 v2 = *(const float4*)(src + 8);
  float4 v3 = *(const float4*)(src + 12);
  s16x8 t0 = { f2bf(v0.x), f2bf(v0.y), f2bf(v0.z), f2bf(v0.w),
               f2bf(v1.x), f2bf(v1.y), f2bf(v1.z), f2bf(v1.w) };
  s16x8 t1 = { f2bf(v2.x), f2bf(v2.y), f2bf(v2.z), f2bf(v2.w),
               f2bf(v3.x), f2bf(v3.y), f2bf(v3.z), f2bf(v3.w) };
  *(s16x8*)(dst)     = t0;
  *(s16x8*)(dst + 8) = t1;
}

// ---------------- init: zero the barrier counters ----------------
__global__ void init_cnt(int* __restrict__ cnt){
  cnt[threadIdx.x] = 0;
}

// ---------------- phase 1: xw = x @ W_in^T + b_in  ->  hid ----------------
__global__ __launch_bounds__(256) void gemm_xw(const float* __restrict__ A,
                                               const float* __restrict__ Wn,
                                               const float* __restrict__ bias,
                                               float* __restrict__ out){
  __shared__ __align__(16) short As[128][40];
  __shared__ __align__(16) short Bs[128][40];
  int bm = blockIdx.x, bn = blockIdx.y;
  int tid = threadIdx.x;
  int lane = tid & 63, wave = tid >> 6;
  int wm = wave >> 1, wn = wave & 1;
  int row0 = bm * 128, col0 = bn * 128;

  f32x4 acc[4][4] = {};
  int sr = tid >> 1, ss = (tid & 1) * 16;

  for (int k0 = 0; k0 < I_; k0 += 32){
    stage16(A  + (size_t)(row0 + sr) * I_ + k0 + ss, &As[sr][ss]);
    stage16(Wn + (size_t)(col0 + sr) * I_ + k0 + ss, &Bs[sr][ss]);
    __syncthreads();

    int rsel = lane & 15, ko = (lane >> 4) * 8;
    s16x8 af[4], bf[4];
    #pragma unroll
    for (int f = 0; f < 4; ++f){
      af[f] = *(const s16x8*)&As[wm*64 + f*16 + rsel][ko];
      bf[f] = *(const s16x8*)&Bs[wn*64 + f*16 + rsel][ko];
    }
    #pragma unroll
    for (int fm = 0; fm < 4; ++fm)
      #pragma unroll
      for (int fn = 0; fn < 4; ++fn)
        acc[fm][fn] = MFMA16(af[fm], bf[fn], acc[fm][fn]);
    __syncthreads();
  }

  int rbase = (lane >> 4) * 4, cbase = lane & 15;
  #pragma unroll
  for (int fm = 0; fm < 4; ++fm)
    #pragma unroll
    for (int fn = 0; fn < 4; ++fn){
      int gcol = col0 + wn*64 + fn*16 + cbase;
      float b = bias[gcol];
      #pragma unroll
      for (int r = 0; r < 4; ++r){
        int grow = row0 + wm*64 + fm*16 + rbase + r;
        out[(size_t)grow * H_ + gcol] = acc[fm][fn][r] + b;
      }
    }
}

// ---------------- phase 2: persistent recurrence, fence-free coherent sync ----
// Grid 256 wgs = 8 batch-groups (bg) x 32 col-groups (cgp). 512 thr = 8 waves:
// wm = wave>>2 (16-row half), kw = wave&3 (K quarter). W_h slice fragment-major
// in LDS (conflict-free ds_read_b128). Cross-wg data (h hi/lo planes) moves via
// sc0/sc1 relaxed-atomic loads/stores only -> NO threadfence (no buffer_wbl2 /
// buffer_inv) anywhere in the loop. __syncthreads drains vmcnt before the
// per-bg monotonic-counter arrive.
__global__ __launch_bounds__(512, 2) void rnn_persistent(float* __restrict__ hid,
                                                         const float* __restrict__ Wh,
                                                         const float* __restrict__ bh,
                                                         short* __restrict__ planes,
                                                         int* __restrict__ cnt){
  __shared__ __align__(16) short Wf[65536];            // 128 KB fragment-major
  __shared__ float redT[2][4][2][4][65];               // scalar-banked K-reduce

  const int PLANE = B_ * H_;                 // 262144 shorts
  int bid = blockIdx.x;
  int bg  = bid >> 5;                        // 0..7
  int cgp = bid & 31;                        // 0..31
  int tid = threadIdx.x;
  int l = tid & 63, wave = tid >> 6;
  int wm = wave >> 2, kw = wave & 3;

  // ---- preload W_h slice, split hi/lo, store fragment-major (once) ----
  #pragma unroll
  for (int it = 0; it < 4; ++it){
    int idx = it * 8192 + tid * 16;          // 32 cols x 1024 k
    int col = idx >> 10;                     // Wh row = output col (0..31)
    int kb  = idx & 1023;                    // multiple of 16
    const float* src = Wh + (size_t)(cgp*32 + col) * H_ + kb;
    int kwW = kb >> 8, kcW = (kb >> 5) & 7, gW = (kb >> 3) & 3;
    int wnW = col >> 4;
    int blk = (kwW*8 + kcW)*4 + wnW*2;       // +p
    #pragma unroll
    for (int h = 0; h < 2; ++h){
      float4 v0 = *(const float4*)(src + h*8);
      float4 v1 = *(const float4*)(src + h*8 + 4);
      float vs[8] = {v0.x, v0.y, v0.z, v0.w, v1.x, v1.y, v1.z, v1.w};
      s16x8 hi8, lo8;
      #pragma unroll
      for (int e = 0; e < 8; ++e){
        short hh = f2bf(vs[e]);
        hi8[e] = hh;
        lo8[e] = f2bf(vs[e] - bf2f(hh));
      }
      int lane16 = ((gW + h) << 4) | (col & 15);
      *(s16x8*)&Wf[(size_t)(blk + 0)*512 + lane16*8] = hi8;
      *(s16x8*)&Wf[(size_t)(blk + 1)*512 + lane16*8] = lo8;
    }
  }
  __syncthreads();

  // ---- per-thread constants ----
  int arow = bg*32 + wm*16 + (l & 15);               // A-frag batch row
  int acol = kw*256 + ((l >> 4) << 3);               // A-frag k offset
  const size_t aoff = (size_t)arow * H_ + acol;
  const short* wb = Wf + kw*16384 + l*8;             // W frag base (this wave)

  // epilogue role: threads 0..255 each own (row erow, 4 consecutive cols)
  int erow  = tid >> 3;                              // 0..31 (wave<4 only)
  int ec0   = (tid & 7) * 4;                         // 0..28
  int growE = bg*32 + erow;
  int gcE   = cgp*32 + ec0;
  float4 biasv = {0.f, 0.f, 0.f, 0.f};
  float4 xwv   = {0.f, 0.f, 0.f, 0.f};
  float* hidRowE = hid + (size_t)growE * T_ * H_;
  if (wave < 4){
    biasv = *(const float4*)(bh + gcE);
    xwv   = *(const float4*)(hidRowE + gcE);         // xw for t = 0
  }

  int* c = cnt + bg * 32;                            // own group's counter

  for (int t = 0; t < T_; ++t){
    if (t > 0){
      // wait for all 32 wgs of this batch group to finish step t-1
      if (tid == 0){
        while (__hip_atomic_load(c, __ATOMIC_RELAXED, __HIP_MEMORY_SCOPE_AGENT) < 32*t)
          __builtin_amdgcn_s_sleep(1);
      }
      __syncthreads();                               // S1

      // A fragments: h_{t-1} hi/lo via coherent loads (fresh from L3)
      const short* aH = planes + (size_t)(t & 1) * 2 * PLANE + aoff;
      const short* aL = aH + PLANE;
      s16x8 ah[8], al[8];
      #pragma unroll
      for (int kc = 0; kc < 8; ++kc) ah[kc] = cload16(aH + kc*32);
      #pragma unroll
      for (int kc = 0; kc < 8; ++kc) al[kc] = cload16(aL + kc*32);

      f32x4 p0 = {}, p1 = {}, p2 = {}, q0 = {}, q1 = {}, q2 = {};
      #pragma unroll
      for (int kc = 0; kc < 8; ++kc){
        s16x8 w0h = *(const s16x8*)(wb + (kc*4 + 0)*512);
        s16x8 w0l = *(const s16x8*)(wb + (kc*4 + 1)*512);
        s16x8 w1h = *(const s16x8*)(wb + (kc*4 + 2)*512);
        s16x8 w1l = *(const s16x8*)(wb + (kc*4 + 3)*512);
        p0 = MFMA16(ah[kc], w0h, p0);
        q0 = MFMA16(ah[kc], w1h, q0);
        p1 = MFMA16(ah[kc], w0l, p1);
        q1 = MFMA16(ah[kc], w1l, q1);
        p2 = MFMA16(al[kc], w0h, p2);
        q2 = MFMA16(al[kc], w1h, q2);
      }
      f32x4 accA = (p0 + p1) + p2;
      f32x4 accB = (q0 + q1) + q2;

      #pragma unroll
      for (int j = 0; j < 4; ++j){
        redT[wm][kw][0][j][l] = accA[j];
        redT[wm][kw][1][j][l] = accB[j];
      }
    }
    __syncthreads();                                 // S2

    if (wave < 4){
      float v[4];
      if (t > 0){
        #pragma unroll
        for (int i = 0; i < 4; ++i){
          int col = ec0 + i;
          int wmE = erow >> 4, wnE = col >> 4;
          int lE  = (((erow & 15) >> 2) << 4) | (col & 15);
          int jE  = erow & 3;
          v[i] = redT[wmE][0][wnE][jE][lE] + redT[wmE][1][wnE][jE][lE]
               + redT[wmE][2][wnE][jE][lE] + redT[wmE][3][wnE][jE][lE];
        }
      } else {
        v[0] = v[1] = v[2] = v[3] = 0.f;
      }
      float xw4[4] = {xwv.x, xwv.y, xwv.z, xwv.w};
      float bi4[4] = {biasv.x, biasv.y, biasv.z, biasv.w};
      union { unsigned long long u; short s[4]; } ph, pl;
      #pragma unroll
      for (int i = 0; i < 4; ++i){
        float vi = v[i] + xw4[i] + bi4[i];
        vi = vi > 0.0f ? vi : 0.0f;
        v[i] = vi;
        short hh = f2bf(vi);
        ph.s[i] = hh;
        pl.s[i] = f2bf(vi - bf2f(hh));
      }
      *(float4*)(hidRowE + (size_t)t * H_ + gcE) = *(const float4*)v;

      short* outHi = planes + (size_t)((t + 1) & 1) * 2 * PLANE
                   + (size_t)growE * H_ + gcE;
      __hip_atomic_store((unsigned long long*)outHi, ph.u,
                         __ATOMIC_RELAXED, __HIP_MEMORY_SCOPE_AGENT);
      __hip_atomic_store((unsigned long long*)(outHi + PLANE), pl.u,
                         __ATOMIC_RELAXED, __HIP_MEMORY_SCOPE_AGENT);
    }

    __syncthreads();                                 // S3: drains vmcnt(0) for
                                                     // ALL threads' sc1 stores
    if (tid == 0) atomicAdd(c, 1);                   // fire-and-forget release

    // prefetch xw(t+1) under the next spin
    if (wave < 4 && t + 1 < T_)
      xwv = *(const float4*)(hidRowE + (size_t)(t + 1) * H_ + gcE);
  }
}

// ---------------- phase 3: out = hidden @ W_o^T + b_o ----------------
__global__ __launch_bounds__(256) void gemm_out(const float* __restrict__ A,
                                                const float* __restrict__ Wo,
                                                const float* __restrict__ bias,
                                                float* __restrict__ out){
  __shared__ __align__(16) short As[128][40];
  __shared__ __align__(16) short Bs[128][40];
  int bm = blockIdx.x;
  int tid = threadIdx.x;
  int lane = tid & 63, wave = tid >> 6;
  int wm = wave >> 1, wn = wave & 1;
  int row0 = bm * 128;

  f32x4 acc[4][4] = {};
  int sr = tid >> 1, ss = (tid & 1) * 16;

  for (int k0 = 0; k0 < H_; k0 += 32){
    stage16(A  + (size_t)(row0 + sr) * H_ + k0 + ss, &As[sr][ss]);
    stage16(Wo + (size_t)sr * H_ + k0 + ss, &Bs[sr][ss]);
    __syncthreads();

    int rsel = lane & 15, ko = (lane >> 4) * 8;
    s16x8 af[4], bf[4];
    #pragma unroll
    for (int f = 0; f < 4; ++f){
      af[f] = *(const s16x8*)&As[wm*64 + f*16 + rsel][ko];
      bf[f] = *(const s16x8*)&Bs[wn*64 + f*16 + rsel][ko];
    }
    #pragma unroll
    for (int fm = 0; fm < 4; ++fm)
      #pragma unroll
      for (int fn = 0; fn < 4; ++fn)
        acc[fm][fn] = MFMA16(af[fm], bf[fn], acc[fm][fn]);
    __syncthreads();
  }

  int rbase = (lane >> 4) * 4, cbase = lane & 15;
  #pragma unroll
  for (int fm = 0; fm < 4; ++fm)
    #pragma unroll
    for (int fn = 0; fn < 4; ++fn){
      int gcol = wn*64 + fn*16 + cbase;
      float b = bias[gcol];
      #pragma unroll
      for (int r = 0; r < 4; ++r){
        int grow = row0 + wm*64 + fm*16 + rbase + r;
        out[(size_t)grow * O_ + gcol] = acc[fm][fn][r] + b;
      }
    }
}

extern "C" void kernel_launch(void* const* d_in, const int* in_sizes, int n_in,
                              void* d_out, int out_size, void* d_ws, size_t ws_size,
                              hipStream_t stream) {
  const float* x    = (const float*)d_in[0];
  const float* W_in = (const float*)d_in[1];
  const float* b_in = (const float*)d_in[2];
  const float* W_h  = (const float*)d_in[3];
  const float* b_h  = (const float*)d_in[4];
  const float* W_o  = (const float*)d_in[5];
  const float* b_o  = (const float*)d_in[6];

  float* out = (float*)d_out;
  float* hid = out + (size_t)BT_ * O_;       // hidden_all region (B,T,H)

  // Scratch inside the (B,T,O) output region (67 MB, dead until phase 3):
  //   planes: 2 slots x (hi+lo) x B_*H_ shorts = 2 MB at offset 0
  //   cnt:    8 barrier counters (32-int stride) at byte offset 4 MB
  short* planes = (short*)d_out;
  int*   cnt    = (int*)(out + (1 << 20));

  init_cnt<<<1, 256, 0, stream>>>(cnt);

  gemm_xw<<<dim3(BT_/128, H_/128), 256, 0, stream>>>(x, W_in, b_in, hid);

  {
    float* hid_p = hid;
    const float* Wh_p = W_h;
    const float* bh_p = b_h;
    short* planes_p = planes;
    int* cnt_p = cnt;
    void* args[] = { &hid_p, &Wh_p, &bh_p, &planes_p, &cnt_p };
    hipLaunchCooperativeKernel((const void*)rnn_persistent,
                               dim3(256), dim3(512), args, 0, stream);
  }

  gemm_out<<<dim3(BT_/128), 256, 0, stream>>>(hid, W_o, b_o, out);
}

// Round 5
// 4585.323 us; speedup vs baseline: 3.9347x; 1.1607x over previous
//
#include <hip/hip_runtime.h>

#define B_ 256
#define T_ 512
#define I_ 512
#define H_ 1024
#define O_ 128
#define BT_ (B_*T_)

typedef short s16x8 __attribute__((ext_vector_type(8)));
typedef float f32x4 __attribute__((ext_vector_type(4)));

#define MFMA16(a,b,c) __builtin_amdgcn_mfma_f32_16x16x32_bf16(a, b, c, 0, 0, 0)

__device__ __forceinline__ short f2bf(float x){
  unsigned u = __float_as_uint(x);
  u = u + 0x7FFFu + ((u >> 16) & 1u);
  return (short)(u >> 16);
}
__device__ __forceinline__ float bf2f(short h){
  return __uint_as_float(((unsigned)(unsigned short)h) << 16);
}

// L2-coherent 16B load: sc0 bypasses L1 only; served by the XCD's shared L2.
// Valid because producer and consumer are guaranteed same-XCD (see negotiation).
__device__ __forceinline__ s16x8 cload16_l2(const short* p){
  s16x8 r;
  asm volatile("global_load_dwordx4 %0, %1, off sc0" : "=v"(r) : "v"(p));
  return r;
}

__device__ __forceinline__ void stage16(const float* __restrict__ src, short* dst){
  float4 v0 = *(const float4*)(src + 0);
  float4 v1 = *(const float4*)(src + 4);
  float4 v2 = *(const float4*)(src + 8);
  float4 v3 = *(const float4*)(src + 12);
  s16x8 t0 = { f2bf(v0.x), f2bf(v0.y), f2bf(v0.z), f2bf(v0.w),
               f2bf(v1.x), f2bf(v1.y), f2bf(v1.z), f2bf(v1.w) };
  s16x8 t1 = { f2bf(v2.x), f2bf(v2.y), f2bf(v2.z), f2bf(v2.w),
               f2bf(v3.x), f2bf(v3.y), f2bf(v3.z), f2bf(v3.w) };
  *(s16x8*)(dst)     = t0;
  *(s16x8*)(dst + 8) = t1;
}

// ---------------- init: zero barrier + role counters ----------------
__global__ void init_cnt(int* __restrict__ cnt){
  cnt[threadIdx.x] = 0;
}

// ---------------- phase 1: xw = x @ W_in^T + b_in  ->  hid ----------------
__global__ __launch_bounds__(256) void gemm_xw(const float* __restrict__ A,
                                               const float* __restrict__ Wn,
                                               const float* __restrict__ bias,
                                               float* __restrict__ out){
  __shared__ __align__(16) short As[128][40];
  __shared__ __align__(16) short Bs[128][40];
  int bm = blockIdx.x, bn = blockIdx.y;
  int tid = threadIdx.x;
  int lane = tid & 63, wave = tid >> 6;
  int wm = wave >> 1, wn = wave & 1;
  int row0 = bm * 128, col0 = bn * 128;

  f32x4 acc[4][4] = {};
  int sr = tid >> 1, ss = (tid & 1) * 16;

  for (int k0 = 0; k0 < I_; k0 += 32){
    stage16(A  + (size_t)(row0 + sr) * I_ + k0 + ss, &As[sr][ss]);
    stage16(Wn + (size_t)(col0 + sr) * I_ + k0 + ss, &Bs[sr][ss]);
    __syncthreads();

    int rsel = lane & 15, ko = (lane >> 4) * 8;
    s16x8 af[4], bf[4];
    #pragma unroll
    for (int f = 0; f < 4; ++f){
      af[f] = *(const s16x8*)&As[wm*64 + f*16 + rsel][ko];
      bf[f] = *(const s16x8*)&Bs[wn*64 + f*16 + rsel][ko];
    }
    #pragma unroll
    for (int fm = 0; fm < 4; ++fm)
      #pragma unroll
      for (int fn = 0; fn < 4; ++fn)
        acc[fm][fn] = MFMA16(af[fm], bf[fn], acc[fm][fn]);
    __syncthreads();
  }

  int rbase = (lane >> 4) * 4, cbase = lane & 15;
  #pragma unroll
  for (int fm = 0; fm < 4; ++fm)
    #pragma unroll
    for (int fn = 0; fn < 4; ++fn){
      int gcol = col0 + wn*64 + fn*16 + cbase;
      float b = bias[gcol];
      #pragma unroll
      for (int r = 0; r < 4; ++r){
        int grow = row0 + wm*64 + fm*16 + rbase + r;
        out[(size_t)grow * H_ + gcol] = acc[fm][fn][r] + b;
      }
    }
}

// ---------------- phase 2: persistent recurrence, XCD-local clusters ----------
// 256 wgs, 1 per CU (128 KB LDS forces it) -> exactly 32 wgs per XCD. Each wg
// reads its XCC_ID and grabs a role: bg = xcd, cgp = role(0..31). All h-plane
// traffic then stays inside one XCD's L2: plain write-back stores + sc0 loads
// (L1 bypass). Only the per-step arrive atomic + spins touch L3.
// 8 waves: wm = wave>>2 (16-row half), kw = wave&3 (K quarter). W_h slice
// fragment-major in LDS (conflict-free ds_read_b128). Per-wave spin on the
// cluster counter replaces the old tid0-spin + broadcast barrier.
__global__ __launch_bounds__(512, 2) void rnn_persistent(float* __restrict__ hid,
                                                         const float* __restrict__ Wh,
                                                         const float* __restrict__ bh,
                                                         short* __restrict__ planes,
                                                         int* __restrict__ cnt){
  __shared__ __align__(16) short Wf[65536];            // 128 KB fragment-major
  __shared__ float redT[2][4][2][4][65];               // scalar-banked K-reduce
  __shared__ int s_role;

  const int PLANE = B_ * H_;                 // 262144 shorts
  int tid = threadIdx.x;
  int l = tid & 63, wave = tid >> 6;
  int wm = wave >> 2, kw = wave & 3;

  // ---- XCD-local role negotiation (once) ----
  int xcd;
  asm("s_getreg_b32 %0, hwreg(HW_REG_XCC_ID)" : "=s"(xcd));
  if (tid == 0)
    s_role = atomicAdd(cnt + (8 + xcd) * 32, 1);
  __syncthreads();
  int bg  = xcd;                             // cluster = this XCD
  int cgp = s_role;                          // 0..31 within the XCD

  // ---- preload W_h slice, split hi/lo, store fragment-major (once) ----
  #pragma unroll
  for (int it = 0; it < 4; ++it){
    int idx = it * 8192 + tid * 16;          // 32 cols x 1024 k
    int col = idx >> 10;                     // Wh row = output col (0..31)
    int kb  = idx & 1023;                    // multiple of 16
    const float* src = Wh + (size_t)(cgp*32 + col) * H_ + kb;
    int kwW = kb >> 8, kcW = (kb >> 5) & 7, gW = (kb >> 3) & 3;
    int wnW = col >> 4;
    int blk = (kwW*8 + kcW)*4 + wnW*2;       // +p
    #pragma unroll
    for (int h = 0; h < 2; ++h){
      float4 v0 = *(const float4*)(src + h*8);
      float4 v1 = *(const float4*)(src + h*8 + 4);
      float vs[8] = {v0.x, v0.y, v0.z, v0.w, v1.x, v1.y, v1.z, v1.w};
      s16x8 hi8, lo8;
      #pragma unroll
      for (int e = 0; e < 8; ++e){
        short hh = f2bf(vs[e]);
        hi8[e] = hh;
        lo8[e] = f2bf(vs[e] - bf2f(hh));
      }
      int lane16 = ((gW + h) << 4) | (col & 15);
      *(s16x8*)&Wf[(size_t)(blk + 0)*512 + lane16*8] = hi8;
      *(s16x8*)&Wf[(size_t)(blk + 1)*512 + lane16*8] = lo8;
    }
  }
  __syncthreads();

  // ---- per-thread constants ----
  int arow = bg*32 + wm*16 + (l & 15);               // A-frag batch row
  int acol = kw*256 + ((l >> 4) << 3);               // A-frag k offset
  const size_t aoff = (size_t)arow * H_ + acol;
  const short* wb = Wf + kw*16384 + l*8;             // W frag base (this wave)

  // epilogue role: threads 0..255 each own (row erow, 4 consecutive cols)
  int erow  = tid >> 3;                              // 0..31 (wave<4 only)
  int ec0   = (tid & 7) * 4;                         // 0..28
  int growE = bg*32 + erow;
  int gcE   = cgp*32 + ec0;
  float4 biasv = {0.f, 0.f, 0.f, 0.f};
  float4 xwv   = {0.f, 0.f, 0.f, 0.f};
  float* hidRowE = hid + (size_t)growE * T_ * H_;
  if (wave < 4){
    biasv = *(const float4*)(bh + gcE);
    xwv   = *(const float4*)(hidRowE + gcE);         // xw for t = 0
  }

  int* c = cnt + bg * 32;                            // own cluster's counter

  for (int t = 0; t < T_; ++t){
    if (t > 0){
      // per-wave spin: proceed as soon as all 32 wgs finished step t-1
      int target = 32 * t;
      while (__hip_atomic_load(c, __ATOMIC_RELAXED, __HIP_MEMORY_SCOPE_AGENT) < target)
        __builtin_amdgcn_s_sleep(1);
      __builtin_amdgcn_sched_barrier(0);

      // A fragments: h_{t-1} hi/lo via sc0 loads (fresh from XCD-local L2)
      const short* aH = planes + (size_t)(t & 1) * 2 * PLANE + aoff;
      const short* aL = aH + PLANE;
      s16x8 ah[8], al[8];
      #pragma unroll
      for (int kc = 0; kc < 8; ++kc) ah[kc] = cload16_l2(aH + kc*32);
      #pragma unroll
      for (int kc = 0; kc < 8; ++kc) al[kc] = cload16_l2(aL + kc*32);
      asm volatile("s_waitcnt vmcnt(0)" ::: "memory");
      __builtin_amdgcn_sched_barrier(0);

      f32x4 p0 = {}, p1 = {}, p2 = {}, q0 = {}, q1 = {}, q2 = {};
      #pragma unroll
      for (int kc = 0; kc < 8; ++kc){
        s16x8 w0h = *(const s16x8*)(wb + (kc*4 + 0)*512);
        s16x8 w0l = *(const s16x8*)(wb + (kc*4 + 1)*512);
        s16x8 w1h = *(const s16x8*)(wb + (kc*4 + 2)*512);
        s16x8 w1l = *(const s16x8*)(wb + (kc*4 + 3)*512);
        p0 = MFMA16(ah[kc], w0h, p0);
        q0 = MFMA16(ah[kc], w1h, q0);
        p1 = MFMA16(ah[kc], w0l, p1);
        q1 = MFMA16(ah[kc], w1l, q1);
        p2 = MFMA16(al[kc], w0h, p2);
        q2 = MFMA16(al[kc], w1h, q2);
      }
      f32x4 accA = (p0 + p1) + p2;
      f32x4 accB = (q0 + q1) + q2;

      #pragma unroll
      for (int j = 0; j < 4; ++j){
        redT[wm][kw][0][j][l] = accA[j];
        redT[wm][kw][1][j][l] = accB[j];
      }
    }
    __syncthreads();                                 // S2

    if (wave < 4){
      float v[4];
      if (t > 0){
        #pragma unroll
        for (int i = 0; i < 4; ++i){
          int col = ec0 + i;
          int wmE = erow >> 4, wnE = col >> 4;
          int lE  = (((erow & 15) >> 2) << 4) | (col & 15);
          int jE  = erow & 3;
          v[i] = redT[wmE][0][wnE][jE][lE] + redT[wmE][1][wnE][jE][lE]
               + redT[wmE][2][wnE][jE][lE] + redT[wmE][3][wnE][jE][lE];
        }
      } else {
        v[0] = v[1] = v[2] = v[3] = 0.f;
      }
      float xw4[4] = {xwv.x, xwv.y, xwv.z, xwv.w};
      float bi4[4] = {biasv.x, biasv.y, biasv.z, biasv.w};
      union { unsigned long long u; short s[4]; } ph, pl;
      #pragma unroll
      for (int i = 0; i < 4; ++i){
        float vi = v[i] + xw4[i] + bi4[i];
        vi = vi > 0.0f ? vi : 0.0f;
        v[i] = vi;
        short hh = f2bf(vi);
        ph.s[i] = hh;
        pl.s[i] = f2bf(vi - bf2f(hh));
      }
      *(float4*)(hidRowE + (size_t)t * H_ + gcE) = *(const float4*)v;

      // plain write-back stores: land in the XCD-local L2 (the coherence
      // point for this cluster); consumers use sc0 loads.
      short* outHi = planes + (size_t)((t + 1) & 1) * 2 * PLANE
                   + (size_t)growE * H_ + gcE;
      *(unsigned long long*)outHi           = ph.u;
      *(unsigned long long*)(outHi + PLANE) = pl.u;
    }

    __syncthreads();                                 // S3: compiler emits
                                                     // vmcnt(0) -> stores in L2
    if (tid == 0) atomicAdd(c, 1);                   // fire-and-forget arrive

    // prefetch xw(t+1) under the next spin
    if (wave < 4 && t + 1 < T_)
      xwv = *(const float4*)(hidRowE + (size_t)(t + 1) * H_ + gcE);
  }
}

// ---------------- phase 3: out = hidden @ W_o^T + b_o ----------------
__global__ __launch_bounds__(256) void gemm_out(const float* __restrict__ A,
                                                const float* __restrict__ Wo,
                                                const float* __restrict__ bias,
                                                float* __restrict__ out){
  __shared__ __align__(16) short As[128][40];
  __shared__ __align__(16) short Bs[128][40];
  int bm = blockIdx.x;
  int tid = threadIdx.x;
  int lane = tid & 63, wave = tid >> 6;
  int wm = wave >> 1, wn = wave & 1;
  int row0 = bm * 128;

  f32x4 acc[4][4] = {};
  int sr = tid >> 1, ss = (tid & 1) * 16;

  for (int k0 = 0; k0 < H_; k0 += 32){
    stage16(A  + (size_t)(row0 + sr) * H_ + k0 + ss, &As[sr][ss]);
    stage16(Wo + (size_t)sr * H_ + k0 + ss, &Bs[sr][ss]);
    __syncthreads();

    int rsel = lane & 15, ko = (lane >> 4) * 8;
    s16x8 af[4], bf[4];
    #pragma unroll
    for (int f = 0; f < 4; ++f){
      af[f] = *(const s16x8*)&As[wm*64 + f*16 + rsel][ko];
      bf[f] = *(const s16x8*)&Bs[wn*64 + f*16 + rsel][ko];
    }
    #pragma unroll
    for (int fm = 0; fm < 4; ++fm)
      #pragma unroll
      for (int fn = 0; fn < 4; ++fn)
        acc[fm][fn] = MFMA16(af[fm], bf[fn], acc[fm][fn]);
    __syncthreads();
  }

  int rbase = (lane >> 4) * 4, cbase = lane & 15;
  #pragma unroll
  for (int fm = 0; fm < 4; ++fm)
    #pragma unroll
    for (int fn = 0; fn < 4; ++fn){
      int gcol = wn*64 + fn*16 + cbase;
      float b = bias[gcol];
      #pragma unroll
      for (int r = 0; r < 4; ++r){
        int grow = row0 + wm*64 + fm*16 + rbase + r;
        out[(size_t)grow * O_ + gcol] = acc[fm][fn][r] + b;
      }
    }
}

extern "C" void kernel_launch(void* const* d_in, const int* in_sizes, int n_in,
                              void* d_out, int out_size, void* d_ws, size_t ws_size,
                              hipStream_t stream) {
  const float* x    = (const float*)d_in[0];
  const float* W_in = (const float*)d_in[1];
  const float* b_in = (const float*)d_in[2];
  const float* W_h  = (const float*)d_in[3];
  const float* b_h  = (const float*)d_in[4];
  const float* W_o  = (const float*)d_in[5];
  const float* b_o  = (const float*)d_in[6];

  float* out = (float*)d_out;
  float* hid = out + (size_t)BT_ * O_;       // hidden_all region (B,T,H)

  // Scratch inside the (B,T,O) output region (67 MB, dead until phase 3):
  //   planes: 2 slots x (hi+lo) x B_*H_ shorts = 2 MB at offset 0
  //   cnt:    8 barrier + 8 role counters (32-int stride) at byte offset 4 MB
  short* planes = (short*)d_out;
  int*   cnt    = (int*)(out + (1 << 20));

  init_cnt<<<1, 512, 0, stream>>>(cnt);

  gemm_xw<<<dim3(BT_/128, H_/128), 256, 0, stream>>>(x, W_in, b_in, hid);

  {
    float* hid_p = hid;
    const float* Wh_p = W_h;
    const float* bh_p = b_h;
    short* planes_p = planes;
    int* cnt_p = cnt;
    void* args[] = { &hid_p, &Wh_p, &bh_p, &planes_p, &cnt_p };
    hipLaunchCooperativeKernel((const void*)rnn_persistent,
                               dim3(256), dim3(512), args, 0, stream);
  }

  gemm_out<<<dim3(BT_/128), 256, 0, stream>>>(hid, W_o, b_o, out);
}

// Round 6
// 4023.033 us; speedup vs baseline: 4.4846x; 1.1398x over previous
//
#include <hip/hip_runtime.h>

#define B_ 256
#define T_ 512
#define I_ 512
#define H_ 1024
#define O_ 128
#define BT_ (B_*T_)

typedef short s16x8 __attribute__((ext_vector_type(8)));
typedef float f32x4 __attribute__((ext_vector_type(4)));

#define MFMA16(a,b,c) __builtin_amdgcn_mfma_f32_16x16x32_bf16(a, b, c, 0, 0, 0)

__device__ __forceinline__ short f2bf(float x){
  unsigned u = __float_as_uint(x);
  u = u + 0x7FFFu + ((u >> 16) & 1u);
  return (short)(u >> 16);
}
__device__ __forceinline__ float bf2f(short h){
  return __uint_as_float(((unsigned)(unsigned short)h) << 16);
}

// L2-coherent 16B load: sc0 bypasses L1 only; served by the XCD's shared L2.
// Valid because producer and consumer are guaranteed same-XCD.
__device__ __forceinline__ s16x8 cload16_l2(const short* p){
  s16x8 r;
  asm volatile("global_load_dwordx4 %0, %1, off sc0" : "=v"(r) : "v"(p));
  return r;
}

__device__ __forceinline__ void stage16(const float* __restrict__ src, short* dst){
  float4 v0 = *(const float4*)(src + 0);
  float4 v1 = *(const float4*)(src + 4);
  float4 v2 = *(const float4*)(src + 8);
  float4 v3 = *(const float4*)(src + 12);
  s16x8 t0 = { f2bf(v0.x), f2bf(v0.y), f2bf(v0.z), f2bf(v0.w),
               f2bf(v1.x), f2bf(v1.y), f2bf(v1.z), f2bf(v1.w) };
  s16x8 t1 = { f2bf(v2.x), f2bf(v2.y), f2bf(v2.z), f2bf(v2.w),
               f2bf(v3.x), f2bf(v3.y), f2bf(v3.z), f2bf(v3.w) };
  *(s16x8*)(dst)     = t0;
  *(s16x8*)(dst + 8) = t1;
}

// ---------------- init: zero flags + role counters (L3-visible) ----------------
// layout in cnt: flags[wg]  at cnt[wg*32], wg = bg*32+cgp (256 of them)
//                roleC[xcd] at cnt[(256+xcd)*32]
__global__ void init_cnt(int* __restrict__ cnt){
  for (int i = threadIdx.x; i < (256 + 8) * 32; i += blockDim.x)
    __hip_atomic_store(cnt + i, 0, __ATOMIC_RELAXED, __HIP_MEMORY_SCOPE_AGENT);
}

// ---------------- phase 1: xw = x @ W_in^T + b_in  ->  hid ----------------
__global__ __launch_bounds__(256) void gemm_xw(const float* __restrict__ A,
                                               const float* __restrict__ Wn,
                                               const float* __restrict__ bias,
                                               float* __restrict__ out){
  __shared__ __align__(16) short As[128][40];
  __shared__ __align__(16) short Bs[128][40];
  int bm = blockIdx.x, bn = blockIdx.y;
  int tid = threadIdx.x;
  int lane = tid & 63, wave = tid >> 6;
  int wm = wave >> 1, wn = wave & 1;
  int row0 = bm * 128, col0 = bn * 128;

  f32x4 acc[4][4] = {};
  int sr = tid >> 1, ss = (tid & 1) * 16;

  for (int k0 = 0; k0 < I_; k0 += 32){
    stage16(A  + (size_t)(row0 + sr) * I_ + k0 + ss, &As[sr][ss]);
    stage16(Wn + (size_t)(col0 + sr) * I_ + k0 + ss, &Bs[sr][ss]);
    __syncthreads();

    int rsel = lane & 15, ko = (lane >> 4) * 8;
    s16x8 af[4], bf[4];
    #pragma unroll
    for (int f = 0; f < 4; ++f){
      af[f] = *(const s16x8*)&As[wm*64 + f*16 + rsel][ko];
      bf[f] = *(const s16x8*)&Bs[wn*64 + f*16 + rsel][ko];
    }
    #pragma unroll
    for (int fm = 0; fm < 4; ++fm)
      #pragma unroll
      for (int fn = 0; fn < 4; ++fn)
        acc[fm][fn] = MFMA16(af[fm], bf[fn], acc[fm][fn]);
    __syncthreads();
  }

  int rbase = (lane >> 4) * 4, cbase = lane & 15;
  #pragma unroll
  for (int fm = 0; fm < 4; ++fm)
    #pragma unroll
    for (int fn = 0; fn < 4; ++fn){
      int gcol = col0 + wn*64 + fn*16 + cbase;
      float b = bias[gcol];
      #pragma unroll
      for (int r = 0; r < 4; ++r){
        int grow = row0 + wm*64 + fm*16 + rbase + r;
        out[(size_t)grow * H_ + gcol] = acc[fm][fn][r] + b;
      }
    }
}

// ---------------- phase 2: persistent recurrence, XCD-local clusters ----------
// 256 wgs, 1 per CU (144 KB LDS forces it) -> 32 wgs per XCD. bg = XCC_ID,
// cgp = per-XCD negotiated role. h planes move via plain write-back stores +
// sc0 loads inside one XCD's L2. Sync: per-wg single-writer monotonic flags
// (128 B apart, sc0sc1 = L3 truth); each wave polls ONLY its 8 producer flags
// (columns kw*256..+256 come from wgs cgp' in [8kw, 8kw+8)).
__global__ __launch_bounds__(512, 2) void rnn_persistent(float* __restrict__ hid,
                                                         const float* __restrict__ Wh,
                                                         const float* __restrict__ bh,
                                                         short* __restrict__ planes,
                                                         int* __restrict__ cnt){
  __shared__ __align__(16) short Wf[65536];            // 128 KB fragment-major
  __shared__ float redT[2][4][2][4][65];               // scalar-banked K-reduce
  __shared__ int s_role;

  const int PLANE = B_ * H_;                 // 262144 shorts
  int tid = threadIdx.x;
  int l = tid & 63, wave = tid >> 6;
  int wm = wave >> 2, kw = wave & 3;

  // ---- XCD-local role negotiation (once) ----
  int xcd;
  asm("s_getreg_b32 %0, hwreg(HW_REG_XCC_ID)" : "=s"(xcd));
  if (tid == 0)
    s_role = atomicAdd(cnt + (256 + xcd) * 32, 1);
  __syncthreads();
  int bg  = xcd;                             // cluster = this XCD
  int cgp = s_role;                          // 0..31 within the XCD

  // ---- preload W_h slice, split hi/lo, store fragment-major (once) ----
  #pragma unroll
  for (int it = 0; it < 4; ++it){
    int idx = it * 8192 + tid * 16;          // 32 cols x 1024 k
    int col = idx >> 10;                     // Wh row = output col (0..31)
    int kb  = idx & 1023;                    // multiple of 16
    const float* src = Wh + (size_t)(cgp*32 + col) * H_ + kb;
    int kwW = kb >> 8, kcW = (kb >> 5) & 7, gW = (kb >> 3) & 3;
    int wnW = col >> 4;
    int blk = (kwW*8 + kcW)*4 + wnW*2;       // +p
    #pragma unroll
    for (int h = 0; h < 2; ++h){
      float4 v0 = *(const float4*)(src + h*8);
      float4 v1 = *(const float4*)(src + h*8 + 4);
      float vs[8] = {v0.x, v0.y, v0.z, v0.w, v1.x, v1.y, v1.z, v1.w};
      s16x8 hi8, lo8;
      #pragma unroll
      for (int e = 0; e < 8; ++e){
        short hh = f2bf(vs[e]);
        hi8[e] = hh;
        lo8[e] = f2bf(vs[e] - bf2f(hh));
      }
      int lane16 = ((gW + h) << 4) | (col & 15);
      *(s16x8*)&Wf[(size_t)(blk + 0)*512 + lane16*8] = hi8;
      *(s16x8*)&Wf[(size_t)(blk + 1)*512 + lane16*8] = lo8;
    }
  }
  __syncthreads();

  // ---- per-thread constants ----
  int arow = bg*32 + wm*16 + (l & 15);               // A-frag batch row
  int acol = kw*256 + ((l >> 4) << 3);               // A-frag k offset
  const size_t aoff = (size_t)arow * H_ + acol;
  const short* wb = Wf + kw*16384 + l*8;             // W frag base (this wave)

  int* ownFlag = cnt + (bg*32 + cgp) * 32;           // this wg's flag
  const int* depF = cnt + (bg*32 + kw*8 + (l & 7)) * 32;  // 8 producer flags

  // epilogue role: threads 0..255 each own (row erow, 4 consecutive cols)
  int erow  = tid >> 3;                              // 0..31 (wave<4 only)
  int ec0   = (tid & 7) * 4;                         // 0..28
  int growE = bg*32 + erow;
  int gcE   = cgp*32 + ec0;
  float4 biasv = {0.f, 0.f, 0.f, 0.f};
  float4 xwv   = {0.f, 0.f, 0.f, 0.f};
  float* hidRowE = hid + (size_t)growE * T_ * H_;
  if (wave < 4){
    biasv = *(const float4*)(bh + gcE);
    xwv   = *(const float4*)(hidRowE + gcE);         // xw for t = 0
  }

  for (int t = 0; t < T_; ++t){
    if (t > 0){
      // wait only for THIS wave's 8 producers to have completed step t-1
      for (;;){
        int f = __hip_atomic_load(depF, __ATOMIC_RELAXED, __HIP_MEMORY_SCOPE_AGENT);
        if (__all(f >= t)) break;
        __builtin_amdgcn_s_sleep(1);
      }
      __builtin_amdgcn_sched_barrier(0);

      // A fragments: h_{t-1} hi/lo via sc0 loads (fresh from XCD-local L2)
      const short* aH = planes + (size_t)(t & 1) * 2 * PLANE + aoff;
      const short* aL = aH + PLANE;
      s16x8 ah[8], al[8];
      #pragma unroll
      for (int kc = 0; kc < 8; ++kc) ah[kc] = cload16_l2(aH + kc*32);
      #pragma unroll
      for (int kc = 0; kc < 8; ++kc) al[kc] = cload16_l2(aL + kc*32);
      asm volatile("s_waitcnt vmcnt(0)" ::: "memory");
      __builtin_amdgcn_sched_barrier(0);

      f32x4 p0 = {}, p1 = {}, p2 = {}, q0 = {}, q1 = {}, q2 = {};
      #pragma unroll
      for (int kc = 0; kc < 8; ++kc){
        s16x8 w0h = *(const s16x8*)(wb + (kc*4 + 0)*512);
        s16x8 w0l = *(const s16x8*)(wb + (kc*4 + 1)*512);
        s16x8 w1h = *(const s16x8*)(wb + (kc*4 + 2)*512);
        s16x8 w1l = *(const s16x8*)(wb + (kc*4 + 3)*512);
        p0 = MFMA16(ah[kc], w0h, p0);
        q0 = MFMA16(ah[kc], w1h, q0);
        p1 = MFMA16(ah[kc], w0l, p1);
        q1 = MFMA16(ah[kc], w1l, q1);
        p2 = MFMA16(al[kc], w0h, p2);
        q2 = MFMA16(al[kc], w1h, q2);
      }
      f32x4 accA = (p0 + p1) + p2;
      f32x4 accB = (q0 + q1) + q2;

      #pragma unroll
      for (int j = 0; j < 4; ++j){
        redT[wm][kw][0][j][l] = accA[j];
        redT[wm][kw][1][j][l] = accB[j];
      }
    }
    __syncthreads();                                 // S2

    if (wave < 4){
      float v[4];
      if (t > 0){
        #pragma unroll
        for (int i = 0; i < 4; ++i){
          int col = ec0 + i;
          int wmE = erow >> 4, wnE = col >> 4;
          int lE  = (((erow & 15) >> 2) << 4) | (col & 15);
          int jE  = erow & 3;
          v[i] = redT[wmE][0][wnE][jE][lE] + redT[wmE][1][wnE][jE][lE]
               + redT[wmE][2][wnE][jE][lE] + redT[wmE][3][wnE][jE][lE];
        }
      } else {
        v[0] = v[1] = v[2] = v[3] = 0.f;
      }
      float xw4[4] = {xwv.x, xwv.y, xwv.z, xwv.w};
      float bi4[4] = {biasv.x, biasv.y, biasv.z, biasv.w};
      union { unsigned long long u; short s[4]; } ph, pl;
      #pragma unroll
      for (int i = 0; i < 4; ++i){
        float vi = v[i] + xw4[i] + bi4[i];
        vi = vi > 0.0f ? vi : 0.0f;
        v[i] = vi;
        short hh = f2bf(vi);
        ph.s[i] = hh;
        pl.s[i] = f2bf(vi - bf2f(hh));
      }
      *(float4*)(hidRowE + (size_t)t * H_ + gcE) = *(const float4*)v;

      // plain write-back stores: land in the XCD-local L2 (the cluster's
      // coherence point); consumers use sc0 loads.
      short* outHi = planes + (size_t)((t + 1) & 1) * 2 * PLANE
                   + (size_t)growE * H_ + gcE;
      *(unsigned long long*)outHi           = ph.u;
      *(unsigned long long*)(outHi + PLANE) = pl.u;
    }

    __syncthreads();                                 // S3: vmcnt(0) drain for
                                                     // all waves' stores
    if (tid == 0)                                    // single-writer arrive
      __hip_atomic_store(ownFlag, t + 1, __ATOMIC_RELAXED, __HIP_MEMORY_SCOPE_AGENT);

    // prefetch xw(t+1) under the next spin
    if (wave < 4 && t + 1 < T_)
      xwv = *(const float4*)(hidRowE + (size_t)(t + 1) * H_ + gcE);
  }
}

// ---------------- phase 3: out = hidden @ W_o^T + b_o ----------------
__global__ __launch_bounds__(256) void gemm_out(const float* __restrict__ A,
                                                const float* __restrict__ Wo,
                                                const float* __restrict__ bias,
                                                float* __restrict__ out){
  __shared__ __align__(16) short As[128][40];
  __shared__ __align__(16) short Bs[128][40];
  int bm = blockIdx.x;
  int tid = threadIdx.x;
  int lane = tid & 63, wave = tid >> 6;
  int wm = wave >> 1, wn = wave & 1;
  int row0 = bm * 128;

  f32x4 acc[4][4] = {};
  int sr = tid >> 1, ss = (tid & 1) * 16;

  for (int k0 = 0; k0 < H_; k0 += 32){
    stage16(A  + (size_t)(row0 + sr) * H_ + k0 + ss, &As[sr][ss]);
    stage16(Wo + (size_t)sr * H_ + k0 + ss, &Bs[sr][ss]);
    __syncthreads();

    int rsel = lane & 15, ko = (lane >> 4) * 8;
    s16x8 af[4], bf[4];
    #pragma unroll
    for (int f = 0; f < 4; ++f){
      af[f] = *(const s16x8*)&As[wm*64 + f*16 + rsel][ko];
      bf[f] = *(const s16x8*)&Bs[wn*64 + f*16 + rsel][ko];
    }
    #pragma unroll
    for (int fm = 0; fm < 4; ++fm)
      #pragma unroll
      for (int fn = 0; fn < 4; ++fn)
        acc[fm][fn] = MFMA16(af[fm], bf[fn], acc[fm][fn]);
    __syncthreads();
  }

  int rbase = (lane >> 4) * 4, cbase = lane & 15;
  #pragma unroll
  for (int fm = 0; fm < 4; ++fm)
    #pragma unroll
    for (int fn = 0; fn < 4; ++fn){
      int gcol = wn*64 + fn*16 + cbase;
      float b = bias[gcol];
      #pragma unroll
      for (int r = 0; r < 4; ++r){
        int grow = row0 + wm*64 + fm*16 + rbase + r;
        out[(size_t)grow * O_ + gcol] = acc[fm][fn][r] + b;
      }
    }
}

extern "C" void kernel_launch(void* const* d_in, const int* in_sizes, int n_in,
                              void* d_out, int out_size, void* d_ws, size_t ws_size,
                              hipStream_t stream) {
  const float* x    = (const float*)d_in[0];
  const float* W_in = (const float*)d_in[1];
  const float* b_in = (const float*)d_in[2];
  const float* W_h  = (const float*)d_in[3];
  const float* b_h  = (const float*)d_in[4];
  const float* W_o  = (const float*)d_in[5];
  const float* b_o  = (const float*)d_in[6];

  float* out = (float*)d_out;
  float* hid = out + (size_t)BT_ * O_;       // hidden_all region (B,T,H)

  // Scratch inside the (B,T,O) output region (67 MB, dead until phase 3):
  //   planes: 2 slots x (hi+lo) x B_*H_ shorts = 2 MB at offset 0
  //   cnt:    256 flags + 8 role counters (128 B stride) at byte offset 4 MB
  short* planes = (short*)d_out;
  int*   cnt    = (int*)(out + (1 << 20));

  init_cnt<<<1, 1024, 0, stream>>>(cnt);

  gemm_xw<<<dim3(BT_/128, H_/128), 256, 0, stream>>>(x, W_in, b_in, hid);

  {
    float* hid_p = hid;
    const float* Wh_p = W_h;
    const float* bh_p = b_h;
    short* planes_p = planes;
    int* cnt_p = cnt;
    void* args[] = { &hid_p, &Wh_p, &bh_p, &planes_p, &cnt_p };
    hipLaunchCooperativeKernel((const void*)rnn_persistent,
                               dim3(256), dim3(512), args, 0, stream);
  }

  gemm_out<<<dim3(BT_/128), 256, 0, stream>>>(hid, W_o, b_o, out);
}

// Round 8
// 3822.979 us; speedup vs baseline: 4.7193x; 1.0523x over previous
//
#include <hip/hip_runtime.h>

#define B_ 256
#define T_ 512
#define I_ 512
#define H_ 1024
#define O_ 128
#define BT_ (B_*T_)

typedef short s16x8 __attribute__((ext_vector_type(8)));
typedef float f32x4 __attribute__((ext_vector_type(4)));

#define MFMA16(a,b,c) __builtin_amdgcn_mfma_f32_16x16x32_bf16(a, b, c, 0, 0, 0)

__device__ __forceinline__ short f2bf(float x){
  unsigned u = __float_as_uint(x);
  u = u + 0x7FFFu + ((u >> 16) & 1u);
  return (short)(u >> 16);
}
__device__ __forceinline__ float bf2f(short h){
  return __uint_as_float(((unsigned)(unsigned short)h) << 16);
}

// sc0-only 16B load: bypasses L1, served by the XCD-shared L2 (producer and
// consumer are guaranteed same-XCD by the role negotiation). Proven in R5/R6.
__device__ __forceinline__ s16x8 cload16_l2(const short* p){
  s16x8 r;
  asm volatile("global_load_dwordx4 %0, %1, off sc0" : "=&v"(r) : "v"(p));
  return r;
}

__device__ __forceinline__ void stage16(const float* __restrict__ src, short* dst){
  float4 v0 = *(const float4*)(src + 0);
  float4 v1 = *(const float4*)(src + 4);
  float4 v2 = *(const float4*)(src + 8);
  float4 v3 = *(const float4*)(src + 12);
  s16x8 t0 = { f2bf(v0.x), f2bf(v0.y), f2bf(v0.z), f2bf(v0.w),
               f2bf(v1.x), f2bf(v1.y), f2bf(v1.z), f2bf(v1.w) };
  s16x8 t1 = { f2bf(v2.x), f2bf(v2.y), f2bf(v2.z), f2bf(v2.w),
               f2bf(v3.x), f2bf(v3.y), f2bf(v3.z), f2bf(v3.w) };
  *(s16x8*)(dst)     = t0;
  *(s16x8*)(dst + 8) = t1;
}

// ---------------- init: zero flags + role counters ----------------
// cnt layout: flags[wg] at cnt[wg*32], wg = bg*32+cgp (256);
//             role counters at cnt[(256+xcd)*32].
__global__ void init_cnt(int* __restrict__ cnt){
  for (int i = threadIdx.x; i < (256 + 8) * 32; i += blockDim.x)
    __hip_atomic_store(cnt + i, 0, __ATOMIC_RELAXED, __HIP_MEMORY_SCOPE_AGENT);
}

// ---------------- phase 1: xw = x @ W_in^T + b_in  ->  hid ----------------
__global__ __launch_bounds__(256) void gemm_xw(const float* __restrict__ A,
                                               const float* __restrict__ Wn,
                                               const float* __restrict__ bias,
                                               float* __restrict__ out){
  __shared__ __align__(16) short As[128][40];
  __shared__ __align__(16) short Bs[128][40];
  int bm = blockIdx.x, bn = blockIdx.y;
  int tid = threadIdx.x;
  int lane = tid & 63, wave = tid >> 6;
  int wm = wave >> 1, wn = wave & 1;
  int row0 = bm * 128, col0 = bn * 128;

  f32x4 acc[4][4] = {};
  int sr = tid >> 1, ss = (tid & 1) * 16;

  for (int k0 = 0; k0 < I_; k0 += 32){
    stage16(A  + (size_t)(row0 + sr) * I_ + k0 + ss, &As[sr][ss]);
    stage16(Wn + (size_t)(col0 + sr) * I_ + k0 + ss, &Bs[sr][ss]);
    __syncthreads();

    int rsel = lane & 15, ko = (lane >> 4) * 8;
    s16x8 af[4], bf[4];
    #pragma unroll
    for (int f = 0; f < 4; ++f){
      af[f] = *(const s16x8*)&As[wm*64 + f*16 + rsel][ko];
      bf[f] = *(const s16x8*)&Bs[wn*64 + f*16 + rsel][ko];
    }
    #pragma unroll
    for (int fm = 0; fm < 4; ++fm)
      #pragma unroll
      for (int fn = 0; fn < 4; ++fn)
        acc[fm][fn] = MFMA16(af[fm], bf[fn], acc[fm][fn]);
    __syncthreads();
  }

  int rbase = (lane >> 4) * 4, cbase = lane & 15;
  #pragma unroll
  for (int fm = 0; fm < 4; ++fm)
    #pragma unroll
    for (int fn = 0; fn < 4; ++fn){
      int gcol = col0 + wn*64 + fn*16 + cbase;
      float b = bias[gcol];
      #pragma unroll
      for (int r = 0; r < 4; ++r){
        int grow = row0 + wm*64 + fm*16 + rbase + r;
        out[(size_t)grow * H_ + gcol] = acc[fm][fn][r] + b;
      }
    }
}

// ---------------- phase 2: persistent recurrence ----------------
// 256 wgs, 1/CU (82.2 KB LDS forces it: 2x82.2 > 160) -> 32 wgs per XCD.
// bg = XCC_ID, cgp = negotiated role. h hi/lo planes flow through the
// XCD-local L2 (plain write-back stores + sc0 loads) - proven R5/R6.
// Sync transport = R6 verbatim: per-wg monotonic flag, tid0 agent-scope
// store after S3; each wave agent-polls only its 8 producer wgs.
// NEW vs R6 (compute only): W-hi fragments live in VGPRs (16 x s16x8/lane),
// only W-lo is read from LDS (halves per-step LDS traffic; 4 of 6 MFMAs
// register-only); epilogue spread across all 8 waves (2 elems/thread).
__global__ __launch_bounds__(512, 2) void rnn_persistent(float* __restrict__ hid,
                                                         const float* __restrict__ Wh,
                                                         const float* __restrict__ bh,
                                                         short* __restrict__ planes,
                                                         int* __restrict__ cnt){
  __shared__ __align__(16) short WfLo[32768];          // 64 KB lo fragments
  __shared__ float redT[2][4][2][4][65];               // 16.25 KB K-reduce
  __shared__ int s_role;

  const int PLANE = B_ * H_;                 // 262144 shorts
  int tid = threadIdx.x;
  int l = tid & 63, wave = tid >> 6;
  int wm = wave >> 2, kw = wave & 3;

  // ---- XCD-local role negotiation (once) ----
  int xcd;
  asm("s_getreg_b32 %0, hwreg(HW_REG_XCC_ID)" : "=s"(xcd));
  if (tid == 0)
    s_role = atomicAdd(cnt + (256 + xcd) * 32, 1);
  __syncthreads();
  int bg  = xcd;
  int cgp = s_role;

  // ---- gather W-hi frags into registers; wm==0 waves write W-lo to LDS ----
  // Fragment layout (matches MFMA B-operand): lane l -> col = l&15,
  // k-offset = (l>>4)*8 within the 32-wide k-chunk kc of K-quarter kw.
  s16x8 whr[16];
  #pragma unroll
  for (int kc = 0; kc < 8; ++kc){
    #pragma unroll
    for (int wn = 0; wn < 2; ++wn){
      const float* s = Wh + (size_t)(cgp*32 + wn*16 + (l & 15)) * H_
                          + kw*256 + kc*32 + ((l >> 4) << 3);
      float4 a0 = *(const float4*)s;
      float4 a1 = *(const float4*)(s + 4);
      float vs[8] = {a0.x, a0.y, a0.z, a0.w, a1.x, a1.y, a1.z, a1.w};
      s16x8 hi8, lo8;
      #pragma unroll
      for (int e = 0; e < 8; ++e){
        short hh = f2bf(vs[e]);
        hi8[e] = hh;
        lo8[e] = f2bf(vs[e] - bf2f(hh));
      }
      whr[kc*2 + wn] = hi8;
      if (wm == 0)
        *(s16x8*)&WfLo[((kw*8 + kc)*2 + wn)*512 + l*8] = lo8;
    }
  }
  __syncthreads();

  // ---- per-thread constants ----
  int arow = bg*32 + wm*16 + (l & 15);               // A-frag batch row
  int acol = kw*256 + ((l >> 4) << 3);               // A-frag k offset
  const size_t aoff = (size_t)arow * H_ + acol;

  // epilogue: thread owns (erow, 2 consecutive cols)
  int erow  = tid >> 4;                              // 0..31
  int ec0   = (tid & 15) * 2;                        // 0..30
  int growE = bg*32 + erow;
  int gcE   = cgp*32 + ec0;
  float2 biasv = *(const float2*)(bh + gcE);
  float* hidRowE = hid + (size_t)growE * T_ * H_;

  int* ownFlag = cnt + (bg*32 + cgp) * 32;           // this wg's flag
  const int* depF = cnt + (bg*32 + kw*8 + (l & 7)) * 32;  // 8 producer flags

  float2 xwv = *(const float2*)(hidRowE + gcE);      // xw for t = 0

  for (int t = 0; t < T_; ++t){
    if (t > 0){
      // wait only for THIS wave's 8 producers to have completed step t-1
      for (;;){
        int f = __hip_atomic_load(depF, __ATOMIC_RELAXED, __HIP_MEMORY_SCOPE_AGENT);
        if (__all(f >= t)) break;
        __builtin_amdgcn_s_sleep(1);
      }
      __builtin_amdgcn_sched_barrier(0);

      // A fragments: h_{t-1} hi/lo via sc0 loads (fresh from XCD-local L2)
      const short* aH = planes + (size_t)(t & 1) * 2 * PLANE + aoff;
      const short* aL = aH + PLANE;
      s16x8 ah[8], al[8];
      #pragma unroll
      for (int kc = 0; kc < 8; ++kc) ah[kc] = cload16_l2(aH + kc*32);
      #pragma unroll
      for (int kc = 0; kc < 8; ++kc) al[kc] = cload16_l2(aL + kc*32);
      asm volatile("s_waitcnt vmcnt(0)" ::: "memory");
      __builtin_amdgcn_sched_barrier(0);

      f32x4 p0 = {}, p1 = {}, p2 = {}, q0 = {}, q1 = {}, q2 = {};
      #pragma unroll
      for (int kc = 0; kc < 8; ++kc){
        s16x8 wl0 = *(const s16x8*)&WfLo[((kw*8 + kc)*2 + 0)*512 + l*8];
        s16x8 wl1 = *(const s16x8*)&WfLo[((kw*8 + kc)*2 + 1)*512 + l*8];
        p0 = MFMA16(ah[kc], whr[kc*2 + 0], p0);
        q0 = MFMA16(ah[kc], whr[kc*2 + 1], q0);
        p1 = MFMA16(ah[kc], wl0, p1);
        q1 = MFMA16(ah[kc], wl1, q1);
        p2 = MFMA16(al[kc], whr[kc*2 + 0], p2);
        q2 = MFMA16(al[kc], whr[kc*2 + 1], q2);
      }
      f32x4 accA = (p0 + p1) + p2;
      f32x4 accB = (q0 + q1) + q2;

      #pragma unroll
      for (int j = 0; j < 4; ++j){
        redT[wm][kw][0][j][l] = accA[j];
        redT[wm][kw][1][j][l] = accB[j];
      }
    }
    __syncthreads();                                 // S2

    // ---- epilogue: all 8 waves, 2 elements per thread ----
    {
      float v0, v1;
      if (t > 0){
        int wmE = erow >> 4;
        int wnE = ec0 >> 4;
        int jE  = erow & 3;
        int lE  = (((erow & 15) >> 2) << 4) | (ec0 & 15);
        v0 = redT[wmE][0][wnE][jE][lE]     + redT[wmE][1][wnE][jE][lE]
           + redT[wmE][2][wnE][jE][lE]     + redT[wmE][3][wnE][jE][lE];
        v1 = redT[wmE][0][wnE][jE][lE + 1] + redT[wmE][1][wnE][jE][lE + 1]
           + redT[wmE][2][wnE][jE][lE + 1] + redT[wmE][3][wnE][jE][lE + 1];
      } else {
        v0 = v1 = 0.f;
      }
      v0 += xwv.x + biasv.x;
      v1 += xwv.y + biasv.y;
      v0 = v0 > 0.0f ? v0 : 0.0f;
      v1 = v1 > 0.0f ? v1 : 0.0f;

      float2 hv = {v0, v1};
      *(float2*)(hidRowE + (size_t)t * H_ + gcE) = hv;

      short h0 = f2bf(v0), h1 = f2bf(v1);
      short lo0 = f2bf(v0 - bf2f(h0)), lo1 = f2bf(v1 - bf2f(h1));
      short* outHi = planes + (size_t)((t + 1) & 1) * 2 * PLANE
                   + (size_t)growE * H_ + gcE;
      *(int*)outHi           = ((unsigned short)h0)  | ((unsigned)(unsigned short)h1  << 16);
      *(int*)(outHi + PLANE) = ((unsigned short)lo0) | ((unsigned)(unsigned short)lo1 << 16);
    }

    __syncthreads();                                 // S3: drains vmcnt(0) for
                                                     // all waves' stores
    if (tid == 0)                                    // single-writer arrive
      __hip_atomic_store(ownFlag, t + 1, __ATOMIC_RELAXED, __HIP_MEMORY_SCOPE_AGENT);

    // prefetch xw(t+1) under the next spin (compiler-managed plain load)
    if (t + 1 < T_)
      xwv = *(const float2*)(hidRowE + (size_t)(t + 1) * H_ + gcE);
  }
}

// ---------------- phase 3: out = hidden @ W_o^T + b_o ----------------
__global__ __launch_bounds__(256) void gemm_out(const float* __restrict__ A,
                                                const float* __restrict__ Wo,
                                                const float* __restrict__ bias,
                                                float* __restrict__ out){
  __shared__ __align__(16) short As[128][40];
  __shared__ __align__(16) short Bs[128][40];
  int bm = blockIdx.x;
  int tid = threadIdx.x;
  int lane = tid & 63, wave = tid >> 6;
  int wm = wave >> 1, wn = wave & 1;
  int row0 = bm * 128;

  f32x4 acc[4][4] = {};
  int sr = tid >> 1, ss = (tid & 1) * 16;

  for (int k0 = 0; k0 < H_; k0 += 32){
    stage16(A  + (size_t)(row0 + sr) * H_ + k0 + ss, &As[sr][ss]);
    stage16(Wo + (size_t)sr * H_ + k0 + ss, &Bs[sr][ss]);
    __syncthreads();

    int rsel = lane & 15, ko = (lane >> 4) * 8;
    s16x8 af[4], bf[4];
    #pragma unroll
    for (int f = 0; f < 4; ++f){
      af[f] = *(const s16x8*)&As[wm*64 + f*16 + rsel][ko];
      bf[f] = *(const s16x8*)&Bs[wn*64 + f*16 + rsel][ko];
    }
    #pragma unroll
    for (int fm = 0; fm < 4; ++fm)
      #pragma unroll
      for (int fn = 0; fn < 4; ++fn)
        acc[fm][fn] = MFMA16(af[fm], bf[fn], acc[fm][fn]);
    __syncthreads();
  }

  int rbase = (lane >> 4) * 4, cbase = lane & 15;
  #pragma unroll
  for (int fm = 0; fm < 4; ++fm)
    #pragma unroll
    for (int fn = 0; fn < 4; ++fn){
      int gcol = wn*64 + fn*16 + cbase;
      float b = bias[gcol];
      #pragma unroll
      for (int r = 0; r < 4; ++r){
        int grow = row0 + wm*64 + fm*16 + rbase + r;
        out[(size_t)grow * O_ + gcol] = acc[fm][fn][r] + b;
      }
    }
}

extern "C" void kernel_launch(void* const* d_in, const int* in_sizes, int n_in,
                              void* d_out, int out_size, void* d_ws, size_t ws_size,
                              hipStream_t stream) {
  const float* x    = (const float*)d_in[0];
  const float* W_in = (const float*)d_in[1];
  const float* b_in = (const float*)d_in[2];
  const float* W_h  = (const float*)d_in[3];
  const float* b_h  = (const float*)d_in[4];
  const float* W_o  = (const float*)d_in[5];
  const float* b_o  = (const float*)d_in[6];

  float* out = (float*)d_out;
  float* hid = out + (size_t)BT_ * O_;       // hidden_all region (B,T,H)

  // Scratch inside the (B,T,O) output region (67 MB, dead until phase 3):
  //   planes: 2 slots x (hi+lo) x B_*H_ shorts = 2 MB at offset 0
  //   cnt:    256 flags + 8 role counters (128 B stride) at byte offset 4 MB
  short* planes = (short*)d_out;
  int*   cnt    = (int*)(out + (1 << 20));

  init_cnt<<<1, 1024, 0, stream>>>(cnt);

  gemm_xw<<<dim3(BT_/128, H_/128), 256, 0, stream>>>(x, W_in, b_in, hid);

  {
    float* hid_p = hid;
    const float* Wh_p = W_h;
    const float* bh_p = b_h;
    short* planes_p = planes;
    int* cnt_p = cnt;
    void* args[] = { &hid_p, &Wh_p, &bh_p, &planes_p, &cnt_p };
    hipLaunchCooperativeKernel((const void*)rnn_persistent,
                               dim3(256), dim3(512), args, 0, stream);
  }

  gemm_out<<<dim3(BT_/128), 256, 0, stream>>>(hid, W_o, b_o, out);
}

// Round 9
// 3477.784 us; speedup vs baseline: 5.1877x; 1.0993x over previous
//
#include <hip/hip_runtime.h>

#define B_ 256
#define T_ 512
#define I_ 512
#define H_ 1024
#define O_ 128
#define BT_ (B_*T_)

typedef short s16x8 __attribute__((ext_vector_type(8)));
typedef float f32x4 __attribute__((ext_vector_type(4)));

#define MFMA16(a,b,c) __builtin_amdgcn_mfma_f32_16x16x32_bf16(a, b, c, 0, 0, 0)

__device__ __forceinline__ short f2bf(float x){
  unsigned u = __float_as_uint(x);
  u = u + 0x7FFFu + ((u >> 16) & 1u);
  return (short)(u >> 16);
}
__device__ __forceinline__ float bf2f(short h){
  return __uint_as_float(((unsigned)(unsigned short)h) << 16);
}

// sc0-only 16B load: bypasses L1, served by the XCD-shared L2 (producer and
// consumer are guaranteed same-XCD by the role negotiation). Proven R5-R8.
__device__ __forceinline__ s16x8 cload16_l2(const short* p){
  s16x8 r;
  asm volatile("global_load_dwordx4 %0, %1, off sc0" : "=&v"(r) : "v"(p));
  return r;
}

__device__ __forceinline__ void stage16(const float* __restrict__ src, short* dst){
  float4 v0 = *(const float4*)(src + 0);
  float4 v1 = *(const float4*)(src + 4);
  float4 v2 = *(const float4*)(src + 8);
  float4 v3 = *(const float4*)(src + 12);
  s16x8 t0 = { f2bf(v0.x), f2bf(v0.y), f2bf(v0.z), f2bf(v0.w),
               f2bf(v1.x), f2bf(v1.y), f2bf(v1.z), f2bf(v1.w) };
  s16x8 t1 = { f2bf(v2.x), f2bf(v2.y), f2bf(v2.z), f2bf(v2.w),
               f2bf(v3.x), f2bf(v3.y), f2bf(v3.z), f2bf(v3.w) };
  *(s16x8*)(dst)     = t0;
  *(s16x8*)(dst + 8) = t1;
}

// ---------------- init: zero flags + role counters ----------------
__global__ void init_cnt(int* __restrict__ cnt){
  for (int i = threadIdx.x; i < (256 + 8) * 32; i += blockDim.x)
    __hip_atomic_store(cnt + i, 0, __ATOMIC_RELAXED, __HIP_MEMORY_SCOPE_AGENT);
}

// ---------------- phase 1: xw = x @ W_in^T + b_in  ->  hid ----------------
__global__ __launch_bounds__(256) void gemm_xw(const float* __restrict__ A,
                                               const float* __restrict__ Wn,
                                               const float* __restrict__ bias,
                                               float* __restrict__ out){
  __shared__ __align__(16) short As[128][40];
  __shared__ __align__(16) short Bs[128][40];
  int bm = blockIdx.x, bn = blockIdx.y;
  int tid = threadIdx.x;
  int lane = tid & 63, wave = tid >> 6;
  int wm = wave >> 1, wn = wave & 1;
  int row0 = bm * 128, col0 = bn * 128;

  f32x4 acc[4][4] = {};
  int sr = tid >> 1, ss = (tid & 1) * 16;

  for (int k0 = 0; k0 < I_; k0 += 32){
    stage16(A  + (size_t)(row0 + sr) * I_ + k0 + ss, &As[sr][ss]);
    stage16(Wn + (size_t)(col0 + sr) * I_ + k0 + ss, &Bs[sr][ss]);
    __syncthreads();

    int rsel = lane & 15, ko = (lane >> 4) * 8;
    s16x8 af[4], bf[4];
    #pragma unroll
    for (int f = 0; f < 4; ++f){
      af[f] = *(const s16x8*)&As[wm*64 + f*16 + rsel][ko];
      bf[f] = *(const s16x8*)&Bs[wn*64 + f*16 + rsel][ko];
    }
    #pragma unroll
    for (int fm = 0; fm < 4; ++fm)
      #pragma unroll
      for (int fn = 0; fn < 4; ++fn)
        acc[fm][fn] = MFMA16(af[fm], bf[fn], acc[fm][fn]);
    __syncthreads();
  }

  int rbase = (lane >> 4) * 4, cbase = lane & 15;
  #pragma unroll
  for (int fm = 0; fm < 4; ++fm)
    #pragma unroll
    for (int fn = 0; fn < 4; ++fn){
      int gcol = col0 + wn*64 + fn*16 + cbase;
      float b = bias[gcol];
      #pragma unroll
      for (int r = 0; r < 4; ++r){
        int grow = row0 + wm*64 + fm*16 + rbase + r;
        out[(size_t)grow * H_ + gcol] = acc[fm][fn][r] + b;
      }
    }
}

// ---------------- phase 2: persistent recurrence ----------------
// 256 wgs, 1/CU (96.6 KB LDS forces it) -> 32 wgs per XCD. bg = XCC_ID,
// cgp = negotiated role. h hi/lo planes + poll flags: transport identical to
// R8 (plain write-back stores + sc0 loads in the XCD L2; per-wg flag, tid0
// agent store after S3; per-wave poll of 8 producer flags).
// R9 (ordering only): W hi AND lo fragments in VGPRs (pure-reg MFMA block);
// hid HBM store deferred to the NEXT step's MFMA shadow; xw(t+1) prefetch in
// the MFMA shadow; S2 is a raw barrier (lgkmcnt-only) so shadow vmem stays
// outstanding until S3 -> the poll and the flag path are vmcnt-clean.
__global__ __launch_bounds__(512, 2) void rnn_persistent(float* __restrict__ hid,
                                                         const float* __restrict__ Wh,
                                                         const float* __restrict__ bh,
                                                         short* __restrict__ planes,
                                                         int* __restrict__ cnt){
  __shared__ __align__(16) short pad[40960];           // 80 KB occupancy pin
  __shared__ float redT[2][4][2][4][65];               // 16.25 KB K-reduce
  __shared__ int s_role;

  const int PLANE = B_ * H_;                 // 262144 shorts
  int tid = threadIdx.x;
  int l = tid & 63, wave = tid >> 6;
  int wm = wave >> 2, kw = wave & 3;

  // ---- XCD-local role negotiation (once) ----
  int xcd;
  asm("s_getreg_b32 %0, hwreg(HW_REG_XCC_ID)" : "=s"(xcd));
  if (tid == 0)
    s_role = atomicAdd(cnt + (256 + xcd) * 32, 1);
  __syncthreads();
  int bg  = xcd;
  int cgp = s_role;
  // keep `pad` allocated (cgp is opaque to the compiler, never >31)
  if (cgp > 31) pad[0] = (short)cgp;

  // ---- gather W hi AND lo fragments into registers (once) ----
  s16x8 whr[16], wlr[16];
  #pragma unroll
  for (int kc = 0; kc < 8; ++kc){
    #pragma unroll
    for (int wn = 0; wn < 2; ++wn){
      const float* s = Wh + (size_t)(cgp*32 + wn*16 + (l & 15)) * H_
                          + kw*256 + kc*32 + ((l >> 4) << 3);
      float4 a0 = *(const float4*)s;
      float4 a1 = *(const float4*)(s + 4);
      float vs[8] = {a0.x, a0.y, a0.z, a0.w, a1.x, a1.y, a1.z, a1.w};
      s16x8 hi8, lo8;
      #pragma unroll
      for (int e = 0; e < 8; ++e){
        short hh = f2bf(vs[e]);
        hi8[e] = hh;
        lo8[e] = f2bf(vs[e] - bf2f(hh));
      }
      whr[kc*2 + wn] = hi8;
      wlr[kc*2 + wn] = lo8;
    }
  }

  // ---- per-thread constants ----
  int arow = bg*32 + wm*16 + (l & 15);               // A-frag batch row
  int acol = kw*256 + ((l >> 4) << 3);               // A-frag k offset
  const size_t aoff = (size_t)arow * H_ + acol;

  // epilogue: thread owns (erow, 2 consecutive cols)
  int erow  = tid >> 4;                              // 0..31
  int ec0   = (tid & 15) * 2;                        // 0..30
  int growE = bg*32 + erow;
  int gcE   = cgp*32 + ec0;
  float2 biasv = *(const float2*)(bh + gcE);
  float* hidRowE = hid + (size_t)growE * T_ * H_;

  int* ownFlag = cnt + (bg*32 + cgp) * 32;           // this wg's flag
  const int* depF = cnt + (bg*32 + kw*8 + (l & 7)) * 32;  // 8 producer flags

  float2 xwv = *(const float2*)(hidRowE + gcE);      // xw(0)
  float2 xwn = {0.f, 0.f};
  float2 vPrev = {0.f, 0.f};

  __syncthreads();                                   // W gather + s_role settled

  for (int t = 0; t < T_; ++t){
    if (t > 0){
      // wait only for THIS wave's 8 producers (vmcnt-clean: everything was
      // drained at the previous S3)
      for (;;){
        int f = __hip_atomic_load(depF, __ATOMIC_RELAXED, __HIP_MEMORY_SCOPE_AGENT);
        if (__all(f >= t)) break;
        __builtin_amdgcn_s_sleep(1);
      }
      __builtin_amdgcn_sched_barrier(0);

      // A fragments: h_{t-1} hi/lo via sc0 loads (XCD-local L2)
      const short* aH = planes + (size_t)(t & 1) * 2 * PLANE + aoff;
      const short* aL = aH + PLANE;
      s16x8 ah[8], al[8];
      #pragma unroll
      for (int kc = 0; kc < 8; ++kc) ah[kc] = cload16_l2(aH + kc*32);
      #pragma unroll
      for (int kc = 0; kc < 8; ++kc) al[kc] = cload16_l2(aL + kc*32);
      asm volatile("s_waitcnt vmcnt(0)" ::: "memory");
      __builtin_amdgcn_sched_barrier(0);

      // ---- MFMA shadow: deferred hid store (t-1) + xw prefetch (t+1) ----
      *(float2*)(hidRowE + (size_t)(t - 1) * H_ + gcE) = vPrev;
      if (t + 1 < T_)
        xwn = *(const float2*)(hidRowE + (size_t)(t + 1) * H_ + gcE);

      f32x4 p0 = {}, p1 = {}, p2 = {}, q0 = {}, q1 = {}, q2 = {};
      #pragma unroll
      for (int kc = 0; kc < 8; ++kc){
        p0 = MFMA16(ah[kc], whr[kc*2 + 0], p0);
        q0 = MFMA16(ah[kc], whr[kc*2 + 1], q0);
        p1 = MFMA16(ah[kc], wlr[kc*2 + 0], p1);
        q1 = MFMA16(ah[kc], wlr[kc*2 + 1], q1);
        p2 = MFMA16(al[kc], whr[kc*2 + 0], p2);
        q2 = MFMA16(al[kc], whr[kc*2 + 1], q2);
      }
      f32x4 accA = (p0 + p1) + p2;
      f32x4 accB = (q0 + q1) + q2;

      #pragma unroll
      for (int j = 0; j < 4; ++j){
        redT[wm][kw][0][j][l] = accA[j];
        redT[wm][kw][1][j][l] = accB[j];
      }
    } else {
      xwn = *(const float2*)(hidRowE + H_ + gcE);    // xw(1)
    }

    // ---- S2: raw barrier, LDS-ordering only (shadow vmem stays in flight) --
    __builtin_amdgcn_sched_barrier(0);
    asm volatile("s_waitcnt lgkmcnt(0)" ::: "memory");
    __builtin_amdgcn_s_barrier();
    __builtin_amdgcn_sched_barrier(0);

    // ---- epilogue: all 8 waves, 2 elements per thread ----
    {
      float v0, v1;
      if (t > 0){
        int wmE = erow >> 4;
        int wnE = ec0 >> 4;
        int jE  = erow & 3;
        int lE  = (((erow & 15) >> 2) << 4) | (ec0 & 15);
        v0 = redT[wmE][0][wnE][jE][lE]     + redT[wmE][1][wnE][jE][lE]
           + redT[wmE][2][wnE][jE][lE]     + redT[wmE][3][wnE][jE][lE];
        v1 = redT[wmE][0][wnE][jE][lE + 1] + redT[wmE][1][wnE][jE][lE + 1]
           + redT[wmE][2][wnE][jE][lE + 1] + redT[wmE][3][wnE][jE][lE + 1];
      } else {
        v0 = v1 = 0.f;
      }
      v0 += xwv.x + biasv.x;
      v1 += xwv.y + biasv.y;
      v0 = v0 > 0.0f ? v0 : 0.0f;
      v1 = v1 > 0.0f ? v1 : 0.0f;

      short h0 = f2bf(v0), h1 = f2bf(v1);
      short lo0 = f2bf(v0 - bf2f(h0)), lo1 = f2bf(v1 - bf2f(h1));
      short* outHi = planes + (size_t)((t + 1) & 1) * 2 * PLANE
                   + (size_t)growE * H_ + gcE;
      *(int*)outHi           = ((unsigned short)h0)  | ((unsigned)(unsigned short)h1  << 16);
      *(int*)(outHi + PLANE) = ((unsigned short)lo0) | ((unsigned)(unsigned short)lo1 << 16);

      float2 hv = {v0, v1};
      vPrev = hv;                                    // hid store deferred
      xwv = xwn;
    }

    __syncthreads();                                 // S3: vmcnt(0) drains
                                                     // planes (+ shadow ops)
    if (tid == 0)                                    // single-writer arrive
      __hip_atomic_store(ownFlag, t + 1, __ATOMIC_RELAXED, __HIP_MEMORY_SCOPE_AGENT);
  }

  // final hid row (T-1) — plain store, drained at kernel end
  *(float2*)(hidRowE + (size_t)(T_ - 1) * H_ + gcE) = vPrev;
}

// ---------------- phase 3: out = hidden @ W_o^T + b_o ----------------
__global__ __launch_bounds__(256) void gemm_out(const float* __restrict__ A,
                                                const float* __restrict__ Wo,
                                                const float* __restrict__ bias,
                                                float* __restrict__ out){
  __shared__ __align__(16) short As[128][40];
  __shared__ __align__(16) short Bs[128][40];
  int bm = blockIdx.x;
  int tid = threadIdx.x;
  int lane = tid & 63, wave = tid >> 6;
  int wm = wave >> 1, wn = wave & 1;
  int row0 = bm * 128;

  f32x4 acc[4][4] = {};
  int sr = tid >> 1, ss = (tid & 1) * 16;

  for (int k0 = 0; k0 < H_; k0 += 32){
    stage16(A  + (size_t)(row0 + sr) * H_ + k0 + ss, &As[sr][ss]);
    stage16(Wo + (size_t)sr * H_ + k0 + ss, &Bs[sr][ss]);
    __syncthreads();

    int rsel = lane & 15, ko = (lane >> 4) * 8;
    s16x8 af[4], bf[4];
    #pragma unroll
    for (int f = 0; f < 4; ++f){
      af[f] = *(const s16x8*)&As[wm*64 + f*16 + rsel][ko];
      bf[f] = *(const s16x8*)&Bs[wn*64 + f*16 + rsel][ko];
    }
    #pragma unroll
    for (int fm = 0; fm < 4; ++fm)
      #pragma unroll
      for (int fn = 0; fn < 4; ++fn)
        acc[fm][fn] = MFMA16(af[fm], bf[fn], acc[fm][fn]);
    __syncthreads();
  }

  int rbase = (lane >> 4) * 4, cbase = lane & 15;
  #pragma unroll
  for (int fm = 0; fm < 4; ++fm)
    #pragma unroll
    for (int fn = 0; fn < 4; ++fn){
      int gcol = wn*64 + fn*16 + cbase;
      float b = bias[gcol];
      #pragma unroll
      for (int r = 0; r < 4; ++r){
        int grow = row0 + wm*64 + fm*16 + rbase + r;
        out[(size_t)grow * O_ + gcol] = acc[fm][fn][r] + b;
      }
    }
}

extern "C" void kernel_launch(void* const* d_in, const int* in_sizes, int n_in,
                              void* d_out, int out_size, void* d_ws, size_t ws_size,
                              hipStream_t stream) {
  const float* x    = (const float*)d_in[0];
  const float* W_in = (const float*)d_in[1];
  const float* b_in = (const float*)d_in[2];
  const float* W_h  = (const float*)d_in[3];
  const float* b_h  = (const float*)d_in[4];
  const float* W_o  = (const float*)d_in[5];
  const float* b_o  = (const float*)d_in[6];

  float* out = (float*)d_out;
  float* hid = out + (size_t)BT_ * O_;       // hidden_all region (B,T,H)

  // Scratch inside the (B,T,O) output region (67 MB, dead until phase 3):
  //   planes: 2 slots x (hi+lo) x B_*H_ shorts = 2 MB at offset 0
  //   cnt:    256 flags + 8 role counters (128 B stride) at byte offset 4 MB
  short* planes = (short*)d_out;
  int*   cnt    = (int*)(out + (1 << 20));

  init_cnt<<<1, 1024, 0, stream>>>(cnt);

  gemm_xw<<<dim3(BT_/128, H_/128), 256, 0, stream>>>(x, W_in, b_in, hid);

  {
    float* hid_p = hid;
    const float* Wh_p = W_h;
    const float* bh_p = b_h;
    short* planes_p = planes;
    int* cnt_p = cnt;
    void* args[] = { &hid_p, &Wh_p, &bh_p, &planes_p, &cnt_p };
    hipLaunchCooperativeKernel((const void*)rnn_persistent,
                               dim3(256), dim3(512), args, 0, stream);
  }

  gemm_out<<<dim3(BT_/128), 256, 0, stream>>>(hid, W_o, b_o, out);
}